// Round 24
// baseline (316.095 us; speedup 1.0000x reference)
//
#include <hip/hip_runtime.h>

// TIBlock: R23 + 128x64 tiles for the six 128-wide chain bmms (WMN=2 path;
// 0.5 KB staged/MFMA vs 1.0). Layer-2 (64-wide) bmms + wglu unchanged.

#define Bn 16
#define Nn 1024
#define C3n 192
static __device__ __constant__ float NORM_C = 0.07216878364870322f; // 1/sqrt(192)

typedef short bf16x8 __attribute__((ext_vector_type(8)));
typedef float f32x4 __attribute__((ext_vector_type(4)));
typedef unsigned short u16;
typedef unsigned short u16x4 __attribute__((ext_vector_type(4)));

__device__ __forceinline__ u16 bf16rn(float x)
{
  unsigned b = __float_as_uint(x);
  b += 0x7fffu + ((b >> 16) & 1u);
  return (u16)(b >> 16);
}
__device__ __forceinline__ float fromh(u16 h) { return __uint_as_float(((unsigned)h) << 16); }

// ------------------------------------------------------------------ MFMA GEMM (bf16 single; SWAP: blockIdx.x=m, .y=n)
template<int TM, int TN, bool OUTB, int BIAS, bool ACC, bool OUTT, bool SWAP>
__global__ __launch_bounds__(256, 2) void mgemm_k(
    const u16* __restrict__ A, long sA, int lda,
    const u16* __restrict__ B, long sB, int ldb,
    const float* __restrict__ bias,
    float* __restrict__ Cf, u16* __restrict__ Cb,
    int M, int N, int K)
{
  constexpr int WMN = (TM >= 128) ? 2 : 1;
  constexpr int WNN = 4 / WMN;
  constexpr int WTM = TM / WMN, WTN = TN / WNN;
  constexpr int FM = WTM / 16, FN = WTN / 16;
  constexpr int BBASE = TM * 128;
  __shared__ __align__(16) char sm[(TM + TN) * 128];

  const int bz = (int)blockIdx.z;
  const int n0 = (SWAP ? blockIdx.y : blockIdx.x) * TN;
  const int m0 = (SWAP ? blockIdx.x : blockIdx.y) * TM;
  const int tid = threadIdx.x, lane = tid & 63, w = tid >> 6;
  const int wm0 = (w / WNN) * WTM, wn0 = (w % WNN) * WTN;

  bf16x8 rA[TM / 32], rB[TN / 32];
  auto loadA = [&](int k0) {
    const u16* p = A + bz * sA + (long)m0 * lda + k0;
#pragma unroll
    for (int i = 0; i < TM / 32; ++i) {
      const int v = tid + i * 256, row = v >> 3, vc = v & 7;
      rA[i] = *(const bf16x8*)(p + (long)row * lda + vc * 8);
    }
  };
  auto storeA = [&]() {
#pragma unroll
    for (int i = 0; i < TM / 32; ++i) {
      const int v = tid + i * 256, row = v >> 3, vc = v & 7;
      *(bf16x8*)(sm + row * 128 + ((vc * 16) ^ ((row & 7) << 4))) = rA[i];
    }
  };
  auto loadB = [&](int k0) {
    const u16* p = B + bz * sB + (long)n0 * ldb + k0;
#pragma unroll
    for (int i = 0; i < TN / 32; ++i) {
      const int v = tid + i * 256, row = v >> 3, vc = v & 7;
      rB[i] = *(const bf16x8*)(p + (long)row * ldb + vc * 8);
    }
  };
  auto storeB = [&]() {
#pragma unroll
    for (int i = 0; i < TN / 32; ++i) {
      const int v = tid + i * 256, row = v >> 3, vc = v & 7;
      *(bf16x8*)(sm + BBASE + row * 128 + ((vc * 16) ^ ((row & 7) << 4))) = rB[i];
    }
  };

  f32x4 acc[FM][FN];
#pragma unroll
  for (int c = 0; c < FM; ++c)
#pragma unroll
    for (int d = 0; d < FN; ++d) acc[c][d] = (f32x4)(0.0f);

  loadA(0); loadB(0);
  for (int k0 = 0; k0 < K; k0 += 64) {
    storeA(); storeB();
    __syncthreads();
    if (k0 + 64 < K) { loadA(k0 + 64); loadB(k0 + 64); }
#pragma unroll
    for (int s = 0; s < 2; ++s) {
      const int kb = s * 64 + ((lane >> 4) << 4);
      bf16x8 ah[FM], bh[FN];
#pragma unroll
      for (int c = 0; c < FM; ++c) {
        const int ar = wm0 + c * 16 + (lane & 15);
        ah[c] = *(const bf16x8*)(sm + ar * 128 + (kb ^ ((ar & 7) << 4)));
      }
#pragma unroll
      for (int d = 0; d < FN; ++d) {
        const int br = wn0 + d * 16 + (lane & 15);
        bh[d] = *(const bf16x8*)(sm + BBASE + br * 128 + (kb ^ ((br & 7) << 4)));
      }
#pragma unroll
      for (int c = 0; c < FM; ++c)
#pragma unroll
        for (int d = 0; d < FN; ++d)
          acc[c][d] = __builtin_amdgcn_mfma_f32_16x16x32_bf16(ah[c], bh[d], acc[c][d], 0, 0, 0);
    }
    __syncthreads();
  }

  const long cb = (long)bz * M * N;
#pragma unroll
  for (int c = 0; c < FM; ++c)
#pragma unroll
    for (int d = 0; d < FN; ++d) {
      const int row0 = m0 + wm0 + c * 16 + (lane >> 4) * 4;
      const int col = n0 + wn0 + d * 16 + (lane & 15);
      if constexpr (OUTT) {
        u16x4 vv;
#pragma unroll
        for (int r = 0; r < 4; ++r) vv[r] = bf16rn(acc[c][d][r]);
        *(u16x4*)(Cb + cb + (long)col * M + row0) = vv;
      } else {
        float bcol = 0.f;
        if constexpr (BIAS == 1) bcol = bias[col];
#pragma unroll
        for (int r = 0; r < 4; ++r) {
          const int row = row0 + r;
          float v = acc[c][d][r];
          if constexpr (BIAS == 1) v += bcol;
          if constexpr (BIAS == 2) v += bias[row];
          const long idx = cb + (long)row * N + col;
          if constexpr (OUTB) {
            Cb[idx] = bf16rn(v);
          } else {
            if constexpr (ACC) v += Cf[idx];
            Cf[idx] = v;
          }
        }
      }
    }
}

// ------------------------------------------------------------------ shared 64x64 GEMM body (merged QKV)
__device__ __forceinline__ void gemm64_body(char* sm,
    const u16* __restrict__ A, int lda, const u16* __restrict__ B, int ldb,
    const float* __restrict__ bias, u16* __restrict__ Cb,
    int N, int K, int m0, int n0, bool biasRow)
{
  const int tid = threadIdx.x, lane = tid & 63, w = tid >> 6;
  bf16x8 rA[2], rB[2];
  auto loadA = [&](int k0) {
#pragma unroll
    for (int i = 0; i < 2; ++i) {
      const int v = tid + i * 256, row = v >> 3, vc = v & 7;
      rA[i] = *(const bf16x8*)(A + (long)(m0 + row) * lda + k0 + vc * 8);
    }
  };
  auto loadB = [&](int k0) {
#pragma unroll
    for (int i = 0; i < 2; ++i) {
      const int v = tid + i * 256, row = v >> 3, vc = v & 7;
      rB[i] = *(const bf16x8*)(B + (long)(n0 + row) * ldb + k0 + vc * 8);
    }
  };
  auto storeAB = [&]() {
#pragma unroll
    for (int i = 0; i < 2; ++i) {
      const int v = tid + i * 256, row = v >> 3, vc = v & 7;
      const int off = row * 128 + ((vc * 16) ^ ((row & 7) << 4));
      *(bf16x8*)(sm + off) = rA[i];
      *(bf16x8*)(sm + 8192 + off) = rB[i];
    }
  };

  f32x4 acc[4];
#pragma unroll
  for (int c = 0; c < 4; ++c) acc[c] = (f32x4)(0.0f);

  loadA(0); loadB(0);
  for (int k0 = 0; k0 < K; k0 += 64) {
    storeAB();
    __syncthreads();
    if (k0 + 64 < K) { loadA(k0 + 64); loadB(k0 + 64); }
#pragma unroll
    for (int s = 0; s < 2; ++s) {
      const int kb = s * 64 + ((lane >> 4) << 4);
      const int br = w * 16 + (lane & 15);
      const bf16x8 bh = *(const bf16x8*)(sm + 8192 + br * 128 + (kb ^ ((br & 7) << 4)));
#pragma unroll
      for (int c = 0; c < 4; ++c) {
        const int ar = c * 16 + (lane & 15);
        const bf16x8 ah = *(const bf16x8*)(sm + ar * 128 + (kb ^ ((ar & 7) << 4)));
        acc[c] = __builtin_amdgcn_mfma_f32_16x16x32_bf16(ah, bh, acc[c], 0, 0, 0);
      }
    }
    __syncthreads();
  }

  const int col = n0 + w * 16 + (lane & 15);
  const float bcol = biasRow ? 0.f : bias[col];
#pragma unroll
  for (int c = 0; c < 4; ++c) {
    const int row0 = m0 + c * 16 + (lane >> 4) * 4;
#pragma unroll
    for (int r = 0; r < 4; ++r) {
      const int row = row0 + r;
      const float bv = biasRow ? bias[row] : bcol;
      Cb[(long)row * N + col] = bf16rn(acc[c][r] + bv);
    }
  }
}

// 6 merged QKV projections in one dispatch: z = p6*16 + b.
__global__ __launch_bounds__(256, 2) void qkv6_k(
    const u16* __restrict__ CNN, const u16* __restrict__ G3,
    const u16* __restrict__ w0, const u16* __restrict__ w1,
    const u16* __restrict__ w2, const u16* __restrict__ w3,
    const u16* __restrict__ w4, const u16* __restrict__ w5,
    const float* __restrict__ b0, const float* __restrict__ b1,
    const float* __restrict__ b2, const float* __restrict__ b3,
    const float* __restrict__ b4, const float* __restrict__ b5,
    u16* __restrict__ o0, u16* __restrict__ o1,
    u16* __restrict__ o2, u16* __restrict__ o3,
    u16* __restrict__ o4, u16* __restrict__ o5)
{
  __shared__ __align__(16) char sm[16384];
  constexpr long QS = (long)Nn * C3n;
  const int z = blockIdx.z, p6 = z >> 4, b = z & 15;
  const u16* in = (p6 == 0 || p6 == 1 || p6 == 4) ? CNN : G3;
  const u16* W = p6==0?w0:p6==1?w1:p6==2?w2:p6==3?w3:p6==4?w4:w5;
  const float* bias = p6==0?b0:p6==1?b1:p6==2?b2:p6==3?b3:p6==4?b4:b5;
  u16* out = p6==0?o0:p6==1?o1:p6==2?o2:p6==3?o3:p6==4?o4:o5;
  if (p6 < 4) {
    gemm64_body(sm, in + (long)b * QS, C3n, W, C3n, bias, out + (long)b * QS,
                C3n, C3n, blockIdx.y * 64, blockIdx.x * 64, false);
  } else {
    gemm64_body(sm, W, C3n, in + (long)b * QS, C3n, bias, out + (long)b * QS,
                Nn, C3n, blockIdx.x * 64, blockIdx.y * 64, true);
  }
}

// ------------------------------------------------------------------ W-mul + GLU fused GEMM (SWAP: blockIdx.x=m, .y=h)
template<int KC, bool OUTT>
__global__ __launch_bounds__(256, 2) void wglu_k(
    const u16* __restrict__ A, long sA,
    const u16* __restrict__ W,
    const float* __restrict__ bias,
    u16* __restrict__ G, long sG, int H)
{
  __shared__ __align__(16) char sm[3 * 8192];
  const int bz = blockIdx.z;
  const int h0 = blockIdx.y * 64, m0 = blockIdx.x * 64;
  const int tid = threadIdx.x, lane = tid & 63, w = tid >> 6;
  const int wn0 = w * 16;

  f32x4 accO[4], accG[4];
#pragma unroll
  for (int c = 0; c < 4; ++c) { accO[c] = (f32x4)(0.0f); accG[c] = (f32x4)(0.0f); }

  for (int k0 = 0; k0 < KC; k0 += 64) {
#pragma unroll
    for (int i = 0; i < 2; ++i) {
      const int v = tid + i * 256, row = v >> 3, vc = v & 7;
      const int off = row * 128 + ((vc * 16) ^ ((row & 7) << 4));
      *(bf16x8*)(sm + off) = *(const bf16x8*)(A + bz * sA + (long)(m0 + row) * KC + k0 + vc * 8);
      *(bf16x8*)(sm + 8192 + off) = *(const bf16x8*)(W + (long)(h0 + row) * KC + k0 + vc * 8);
      *(bf16x8*)(sm + 16384 + off) = *(const bf16x8*)(W + (long)(H + h0 + row) * KC + k0 + vc * 8);
    }
    __syncthreads();
#pragma unroll
    for (int s = 0; s < 2; ++s) {
      const int kb = s * 64 + ((lane >> 4) << 4);
      const int br = wn0 + (lane & 15);
      const bf16x8 bo = *(const bf16x8*)(sm + 8192 + br * 128 + (kb ^ ((br & 7) << 4)));
      const bf16x8 bg = *(const bf16x8*)(sm + 16384 + br * 128 + (kb ^ ((br & 7) << 4)));
#pragma unroll
      for (int c = 0; c < 4; ++c) {
        const int ar = c * 16 + (lane & 15);
        const bf16x8 a = *(const bf16x8*)(sm + ar * 128 + (kb ^ ((ar & 7) << 4)));
        accO[c] = __builtin_amdgcn_mfma_f32_16x16x32_bf16(a, bo, accO[c], 0, 0, 0);
        accG[c] = __builtin_amdgcn_mfma_f32_16x16x32_bf16(a, bg, accG[c], 0, 0, 0);
      }
    }
    __syncthreads();
  }

  const int col = h0 + wn0 + (lane & 15);
  const float bo = bias[col], bg = bias[H + col];
#pragma unroll
  for (int c = 0; c < 4; ++c) {
    const int row0 = m0 + c * 16 + (lane >> 4) * 4;
    if constexpr (OUTT) {
      u16x4 vv;
#pragma unroll
      for (int r = 0; r < 4; ++r) {
        const float o = accO[c][r] + bo, g = accG[c][r] + bg;
        vv[r] = bf16rn(o / (1.f + expf(-g)));
      }
      *(u16x4*)(G + bz * sG + (long)col * Nn + row0) = vv;
    } else {
#pragma unroll
      for (int r = 0; r < 4; ++r) {
        const float o = accO[c][r] + bo, g = accG[c][r] + bg;
        G[bz * sG + (long)(row0 + r) * H + col] = bf16rn(o / (1.f + expf(-g)));
      }
    }
  }
}

// ------------------------------------------------------------------ conv1d k=7 + fused GLU epilogue (R23-proven)
__global__ __launch_bounds__(256, 2) void conv_mfma_k(
    const u16* __restrict__ Wp, const u16* __restrict__ in_nm, int ldin, long sIn,
    const float* __restrict__ bias,
    u16* __restrict__ G, int Ci, int M)
{
  __shared__ __align__(16) char sm[9216 + 7 * 8192];
  const int bz = blockIdx.z;
  const int n0 = blockIdx.x * 64, m0 = blockIdx.y * 64;
  const int tid = threadIdx.x, lane = tid & 63, w = tid >> 6;
  const int wm = (w >> 1) * 32, wn = (w & 1) * 32;
  const u16* inb = in_nm + bz * sIn;

  f32x4 acc[2][2];
#pragma unroll
  for (int c = 0; c < 2; ++c)
#pragma unroll
    for (int d = 0; d < 2; ++d) acc[c][d] = (f32x4)(0.0f);

  for (int k0 = 0; k0 < Ci; k0 += 64) {
#pragma unroll
    for (int r = 0; r < 3; ++r) {
      const int idx = r * 256 + tid;
      if (idx < 576) {
        const int row = idx >> 3, ch = idx & 7;
        const int g = n0 + row - 3;
        bf16x8 v;
#pragma unroll
        for (int j = 0; j < 8; ++j) v[j] = 0;
        if ((unsigned)g < (unsigned)Nn)
          v = *(const bf16x8*)(inb + (long)g * ldin + k0 + ch * 8);
        *(bf16x8*)(sm + row * 128 + ((ch * 16) ^ ((row & 7) << 4))) = v;
      }
    }
#pragma unroll
    for (int i = 0; i < 14; ++i) {
      const int v = tid + i * 256;
      const int ft = v >> 9, rr = (v >> 3) & 63, vc = v & 7;
      const bf16x8 t = *(const bf16x8*)(Wp + ((long)ft * M + m0 + rr) * Ci + k0 + vc * 8);
      *(bf16x8*)(sm + 9216 + ft * 8192 + rr * 128 + ((vc * 16) ^ ((rr & 7) << 4))) = t;
    }
    __syncthreads();
#pragma unroll
    for (int ft = 0; ft < 7; ++ft) {
#pragma unroll
      for (int s = 0; s < 2; ++s) {
        const int kb = s * 64 + ((lane >> 4) << 4);
        bf16x8 ah[2], bh[2];
#pragma unroll
        for (int c = 0; c < 2; ++c) {
          const int ar = wm + c * 16 + (lane & 15);
          ah[c] = *(const bf16x8*)(sm + 9216 + ft * 8192 + ar * 128 + (kb ^ ((ar & 7) << 4)));
          const int hr = wn + c * 16 + (lane & 15) + ft;
          bh[c] = *(const bf16x8*)(sm + hr * 128 + (kb ^ ((hr & 7) << 4)));
        }
#pragma unroll
        for (int c = 0; c < 2; ++c)
#pragma unroll
          for (int d = 0; d < 2; ++d)
            acc[c][d] = __builtin_amdgcn_mfma_f32_16x16x32_bf16(ah[c], bh[d], acc[c][d], 0, 0, 0);
      }
    }
    __syncthreads();
  }

  const int Hh = M >> 1;
  u16* Gb = G + (long)bz * Nn * Hh;
#pragma unroll
  for (int c = 0; c < 2; ++c)
#pragma unroll
    for (int d = 0; d < 2; ++d) {
      const int row0 = m0 + wm + c * 16 + (lane >> 4) * 4;
      const int col = n0 + wn + d * 16 + (lane & 15);
      const int h0 = row0 >> 1;
#pragma unroll
      for (int i = 0; i < 2; ++i) {
        const int h = h0 + i;
        const float o = acc[c][d][2 * i]     + bias[h];
        const float g = acc[c][d][2 * i + 1] + bias[Hh + h];
        Gb[(long)col * Hh + h] = bf16rn(o / (1.f + expf(-g)));
      }
    }
}

// ------------------------------------------------------------------ fused flash attention (R20-proven)
__global__ __launch_bounds__(256, 2) void attn_k(
    const u16* __restrict__ Q0, const u16* __restrict__ K0,
    const u16* __restrict__ V0,
    const u16* __restrict__ Q1, const u16* __restrict__ K1,
    const u16* __restrict__ V1,
    float* __restrict__ PSUM)
{
  constexpr long QS = (long)Nn * C3n;
  constexpr int SMV = 24576, SMP = 49152;
  __shared__ __align__(16) char sm[57344];
  const int combo = blockIdx.x, qb = blockIdx.y;
  const int b = combo & 15, at = combo >> 4;
  const u16* Q = (at ? Q1 : Q0) + (long)b * QS + (long)qb * 64 * C3n;
  const u16* K = (at ? K1 : K0) + (long)b * QS;
  const u16* V = (at ? V1 : V0) + (long)b * QS;
  const int tid = threadIdx.x, lane = tid & 63, w = tid >> 6;

  bf16x8 vone;
#pragma unroll
  for (int j = 0; j < 8; ++j) vone[j] = (short)0x3F80;

  bf16x8 rQ[6];
  {
    const int qrow = w * 16 + (lane & 15);
#pragma unroll
    for (int s = 0; s < 6; ++s)
      rQ[s] = *(const bf16x8*)(Q + (long)qrow * C3n + s * 32 + ((lane >> 4) << 3));
  }

  bf16x8 rK[6], rV[6];
  auto loadK = [&](int kb) {
    const int row = tid >> 2;
#pragma unroll
    for (int j = 0; j < 6; ++j) {
      const int ch = (tid & 3) + j * 4;
      rK[j] = *(const bf16x8*)(K + ((long)kb * 64 + row) * C3n + ch * 8);
    }
  };
  auto storeK = [&]() {
    const int row = tid >> 2;
#pragma unroll
    for (int j = 0; j < 6; ++j) {
      const int ch = (tid & 3) + j * 4;
      *(bf16x8*)(sm + row * 384 + ((ch * 16) ^ ((row & 7) << 4))) = rK[j];
    }
  };
  auto loadV = [&](int kb) {
#pragma unroll
    for (int j = 0; j < 6; ++j) {
      const int row = (tid >> 3) + j * 32;
      const int ch = tid & 7;
      rV[j] = *(const bf16x8*)(V + (long)row * Nn + kb * 64 + ch * 8);
    }
  };
  auto storeV = [&]() {
#pragma unroll
    for (int j = 0; j < 6; ++j) {
      const int row = (tid >> 3) + j * 32;
      const int ch = tid & 7;
      *(bf16x8*)(sm + SMV + row * 128 + ((ch * 16) ^ ((row & 7) << 4))) = rV[j];
    }
  };

  f32x4 accO[12], accL;
#pragma unroll
  for (int f = 0; f < 12; ++f) accO[f] = (f32x4)(0.0f);
  accL = (f32x4)(0.0f);
  float m[4];
#pragma unroll
  for (int r = 0; r < 4; ++r) m[r] = -3.0e38f;

  loadK(0);
  for (int kb = 0; kb < 16; ++kb) {
    storeK();
    __syncthreads();                 // B1
    loadV(kb);

    f32x4 accS[4];
#pragma unroll
    for (int d = 0; d < 4; ++d) accS[d] = (f32x4)(0.0f);
    __builtin_amdgcn_s_setprio(1);
#pragma unroll
    for (int s = 0; s < 6; ++s) {
      const int kpos = s * 64 + ((lane >> 4) << 4);
#pragma unroll
      for (int d = 0; d < 4; ++d) {
        const int br = d * 16 + (lane & 15);
        const bf16x8 bb = *(const bf16x8*)(sm + br * 384 + (kpos ^ ((br & 7) << 4)));
        accS[d] = __builtin_amdgcn_mfma_f32_16x16x32_bf16(rQ[s], bb, accS[d], 0, 0, 0);
      }
    }
    __builtin_amdgcn_s_setprio(0);

    float fac[4];
    bool need = false;
#pragma unroll
    for (int r = 0; r < 4; ++r) {
      float mx = fmaxf(fmaxf(accS[0][r], accS[1][r]), fmaxf(accS[2][r], accS[3][r]));
#pragma unroll
      for (int off = 8; off; off >>= 1) mx = fmaxf(mx, __shfl_xor(mx, off));
      float mn;
      if (mx > m[r] + 8.f) {
        mn = mx;
        fac[r] = __expf(m[r] - mn);
        m[r] = mn;
        need = true;
      } else {
        mn = m[r];
        fac[r] = 1.f;
      }
#pragma unroll
      for (int d = 0; d < 4; ++d) {
        float e = __expf(accS[d][r] - mn);
        if (e != e) e = (accS[d][r] == mn) ? 1.f : 0.f;
        accS[d][r] = e;
      }
    }
    if (__any(need)) {
#pragma unroll
      for (int f = 0; f < 12; ++f)
#pragma unroll
        for (int r = 0; r < 4; ++r) accO[f][r] *= fac[r];
#pragma unroll
      for (int r = 0; r < 4; ++r) accL[r] *= fac[r];
    }

    {
      const int qbase = w * 16 + (lane >> 4) * 4;
#pragma unroll
      for (int r = 0; r < 4; ++r) {
        const int qr = qbase + r;
#pragma unroll
        for (int d = 0; d < 4; ++d) {
          const int colb = (d * 16 + (lane & 15)) * 2;
          *(u16*)(sm + SMP + qr * 128 + (colb ^ ((qr & 7) << 4))) = bf16rn(accS[d][r]);
        }
      }
    }
    storeV();
    __syncthreads();                 // B2
    if (kb < 15) loadK(kb + 1);

    __builtin_amdgcn_s_setprio(1);
#pragma unroll
    for (int s = 0; s < 2; ++s) {
      const int kpos = s * 64 + ((lane >> 4) << 4);
      const int ar = w * 16 + (lane & 15);
      const bf16x8 a = *(const bf16x8*)(sm + SMP + ar * 128 + (kpos ^ ((ar & 7) << 4)));
#pragma unroll
      for (int f = 0; f < 12; ++f) {
        const int br = f * 16 + (lane & 15);
        const bf16x8 bb = *(const bf16x8*)(sm + SMV + br * 128 + (kpos ^ ((br & 7) << 4)));
        accO[f] = __builtin_amdgcn_mfma_f32_16x16x32_bf16(a, bb, accO[f], 0, 0, 0);
      }
      accL = __builtin_amdgcn_mfma_f32_16x16x32_bf16(a, vone, accL, 0, 0, 0);
    }
    __builtin_amdgcn_s_setprio(0);
  }

  float inv[4];
#pragma unroll
  for (int r = 0; r < 4; ++r) inv[r] = NORM_C / accL[r];
  float s[12];
#pragma unroll
  for (int f = 0; f < 12; ++f) {
    s[f] = accO[f][0] * inv[0] + accO[f][1] * inv[1]
         + accO[f][2] * inv[2] + accO[f][3] * inv[3];
    s[f] += __shfl_xor(s[f], 16);
    s[f] += __shfl_xor(s[f], 32);
  }
  __syncthreads();
  float* red = (float*)sm;
  if ((lane >> 4) == 0) {
#pragma unroll
    for (int f = 0; f < 12; ++f) red[w * 192 + f * 16 + (lane & 15)] = s[f];
  }
  __syncthreads();
  if (tid < 192) {
    const float t = red[tid] + red[192 + tid] + red[384 + tid] + red[576 + tid];
    PSUM[(((long)at * 16 + b) * 16 + qb) * 192 + tid] = t;
  }
}

// ------------------------------------------------------------------ merged converters
__global__ void cvt2_k(const float* __restrict__ a, const float* __restrict__ b,
                       u16* __restrict__ da, u16* __restrict__ db, long half4)
{
  const long i = (long)blockIdx.x * 256 + threadIdx.x;
  if (i >= 2 * half4) return;
  const bool second = (i >= half4);
  const long j = second ? i - half4 : i;
  float4 v = ((const float4*)(second ? b : a))[j];
  u16x4 o = {bf16rn(v.x), bf16rn(v.y), bf16rn(v.z), bf16rn(v.w)};
  ((u16x4*)(second ? db : da))[j] = o;
}

__global__ void xcvt2_k(const float* __restrict__ x, u16* __restrict__ xh,
                        u16* __restrict__ xc)
{
  __shared__ float t[32][33];
  const int b = blockIdx.z;
  const int n0 = blockIdx.x * 32, c0 = blockIdx.y * 32;
  const int tx = threadIdx.x, ty = threadIdx.y;
#pragma unroll
  for (int i = 0; i < 32; i += 8) {
    const float v = x[((long)b * Nn + n0 + ty + i) * 128 + c0 + tx];
    t[ty + i][tx] = v;
    xh[((long)b * Nn + n0 + ty + i) * 128 + c0 + tx] = bf16rn(v);
  }
  __syncthreads();
#pragma unroll
  for (int i = 0; i < 32; i += 8)
    xc[((long)b * 128 + c0 + ty + i) * Nn + n0 + tx] = bf16rn(t[tx][ty + i]);
}

// 12 merged weight-prep jobs; conv Wp rows interleaved (2h / 2h+1)
__global__ void prep12_k(
    const float* c1w, const float* c2w, const float* c3w,
    u16* wp1, u16* wp2, u16* wp3,
    const float* q0, const float* q1, const float* q2,
    const float* q3, const float* q4, const float* q5,
    u16* d0, u16* d1, u16* d2, u16* d3, u16* d4, u16* d5,
    const float* g1w, const float* g2w, const float* g3w,
    u16* w1t, u16* w2t, u16* w3t)
{
  const int job = blockIdx.y;
  const int idx = blockIdx.x * 256 + threadIdx.x;
  if (job < 3) {
    const float* w = job == 0 ? c1w : job == 1 ? c2w : c3w;
    u16* Wp = job == 0 ? wp1 : job == 1 ? wp2 : wp3;
    const int Co = job == 0 ? 128 : job == 1 ? 256 : 384;
    const int Ci = job == 1 ? 64 : 128;
    if (idx >= Co * Ci * 7) return;
    const int ft = idx / (Co * Ci);
    const int rem = idx - ft * Co * Ci;
    const int co = rem / Ci, ci = rem - co * Ci;
    const int Hh = Co >> 1;
    const int rnew = (co < Hh) ? (2 * co) : (2 * (co - Hh) + 1);
    Wp[((long)ft * Co + rnew) * Ci + ci] = bf16rn(w[((long)co * Ci + ci) * 7 + ft]);
  } else if (job < 9) {
    const int q = job - 3;
    const float* s = q==0?q0:q==1?q1:q==2?q2:q==3?q3:q==4?q4:q5;
    u16* d = q==0?d0:q==1?d1:q==2?d2:q==3?d3:q==4?d4:d5;
    if (idx >= 192 * 192) return;
    d[idx] = bf16rn(s[idx]);
  } else {
    const int t = job - 9;
    const float* W = t == 0 ? g1w : t == 1 ? g2w : g3w;
    u16* Wt = t == 0 ? w1t : t == 1 ? w2t : w3t;
    const int R = t == 0 ? 128 : t == 1 ? 64 : 128;
    const int C = t == 0 ? 128 : t == 1 ? 256 : 384;
    if (idx >= R * C) return;
    const int c = idx / R, r = idx - c * R;
    Wt[idx] = bf16rn(W[(long)r * C + c]);
  }
}

// ------------------------------------------------------------------ head (sums PSUM partials)
__device__ __forceinline__ float sanitize(float v)
{
  if (v != v) return 0.f;
  return fminf(fmaxf(v, -3.0e38f), 3.0e38f);
}

__global__ void head_k(const float* __restrict__ psum,
                       const float* __restrict__ l1w, const float* __restrict__ l1b,
                       const float* __restrict__ l2w, const float* __restrict__ l2b,
                       const float* __restrict__ eps, float* __restrict__ out)
{
  const int b = blockIdx.x, o = threadIdx.x;
  __shared__ float sp[C3n];
  float sacc = 0.f;
#pragma unroll
  for (int at = 0; at < 2; ++at)
    for (int q = 0; q < 16; ++q)
      sacc += psum[(((long)at * 16 + b) * 16 + q) * 192 + o];
  sp[o] = sacc * (1.f / Nn);
  __syncthreads();
  float d1 = l1b[o], d2 = l2b[o];
  for (int c = 0; c < C3n; ++c) {
    d1 = fmaf(sp[c], l1w[o * C3n + c], d1);
    d2 = fmaf(sp[c], l2w[o * C3n + c], d2);
  }
  const float o1 = fmaxf(d1, 0.f);
  const float o2 = fmaxf(d2, 0.f);
  const float sd = fminf(expf(0.5f * o2), 3.0e38f);
  const double v0 = (double)eps[b * C3n + o] * (double)sd + (double)o1;
  out[b * C3n + o] = sanitize((float)fmin(fmax(v0, -3.0e38), 3.0e38));
  out[Bn * C3n + b * C3n + o] = sanitize(o1);
  out[2 * Bn * C3n + b * C3n + o] = sanitize(o2);
}

// ------------------------------------------------------------------ launch
extern "C" void kernel_launch(void* const* d_in, const int* in_sizes, int n_in,
                              void* d_out, int out_size, void* d_ws, size_t ws_size,
                              hipStream_t stream)
{
  const float* x    = (const float*)d_in[0];
  const float* adjm = (const float*)d_in[1];
  const float* deg  = (const float*)d_in[2];
  const float* eps  = (const float*)d_in[3];
  const float* g1w  = (const float*)d_in[4];
  const float* g1b  = (const float*)d_in[5];
  const float* g2w  = (const float*)d_in[6];
  const float* g2b  = (const float*)d_in[7];
  const float* g3w  = (const float*)d_in[8];
  const float* g3b  = (const float*)d_in[9];
  const float* c1w  = (const float*)d_in[10];
  const float* c1b  = (const float*)d_in[11];
  const float* c2w  = (const float*)d_in[12];
  const float* c2b  = (const float*)d_in[13];
  const float* c3w  = (const float*)d_in[14];
  const float* c3b  = (const float*)d_in[15];
  const float* srqw = (const float*)d_in[16];
  const float* srqb = (const float*)d_in[17];
  const float* srkw = (const float*)d_in[18];
  const float* srkb = (const float*)d_in[19];
  const float* srvw = (const float*)d_in[20];
  const float* srvb = (const float*)d_in[21];
  const float* drqw = (const float*)d_in[22];
  const float* drqb = (const float*)d_in[23];
  const float* drkw = (const float*)d_in[24];
  const float* drkb = (const float*)d_in[25];
  const float* drvw = (const float*)d_in[26];
  const float* drvb = (const float*)d_in[27];
  const float* l1w  = (const float*)d_in[28];
  const float* l1b  = (const float*)d_in[29];
  const float* l2w  = (const float*)d_in[30];
  const float* l2b  = (const float*)d_in[31];
  float* out = (float*)d_out;
  char* ws = (char*)d_ws;

  constexpr long MBc = 1L << 20;
  u16*  DEGB = (u16*)(ws + 0*MBc);
  u16*  ADJB = (u16*)(ws + 34*MBc);
  u16*  c1b16= (u16*)(ws + 94*MBc);
  u16*  c2b16= (u16*)(ws + 97*MBc);
  u16*  T1   = (u16*)(ws + 94*MBc);
  u16*  T2   = (u16*)(ws + 99*MBc);
  u16*  Pb   = (u16*)(ws + 104*MBc);
  u16*  CNN  = (u16*)(ws + 109*MBc);
  u16*  G3   = (u16*)(ws + 116*MBc);
  u16*  xh   = (u16*)(ws + 123*MBc);
  u16*  xch  = (u16*)(ws + 128*MBc);
  u16*  G1   = (u16*)(ws + 133*MBc);
  u16*  G2   = (u16*)(ws + 136*MBc);
  u16*  SRQ = (u16*)(ws + 0*MBc);
  u16*  SRK = (u16*)(ws + 7*MBc);
  u16*  DRQ = (u16*)(ws + 14*MBc);
  u16*  DRK = (u16*)(ws + 21*MBc);
  u16*  SRV = (u16*)(ws + 28*MBc);
  u16*  DRV = (u16*)(ws + 35*MBc);
  float* PSUM = (float*)(ws + 43*MBc); // [2][16][16][192] = 393KB

  long wb = 141 * MBc;
  auto aU = [&](long elems) { u16* p = (u16*)(ws + wb); wb += elems * 2; wb = (wb + 255) & ~255L; return p; };
  u16* W1t = aU(128*128);
  u16* W2t = aU(256*64);
  u16* W3t = aU(384*128);
  u16* WP1 = aU(7*128*128);
  u16* WP2 = aU(7*256*64);
  u16* WP3 = aU(7*384*128);
  u16* QW[6];
  for (int i = 0; i < 6; ++i) QW[i] = aU(192*192);

  const long sNN = (long)Nn * Nn;
  const long QS = (long)Nn * C3n;
  const long sCM128 = (long)128 * Nn;

  // ---------------- P0: conversions + weight prep + CNN branch ----------------
  cvt2_k<<<32768, 256, 0, stream>>>(deg, adjm, DEGB, ADJB, sNN * Bn / 4);
  xcvt2_k<<<dim3(32,4,Bn), dim3(32,8), 0, stream>>>(x, xh, xch);
  prep12_k<<<dim3(1344, 12), 256, 0, stream>>>(
      c1w, c2w, c3w, WP1, WP2, WP3,
      srqw, srkw, srvw, drqw, drkw, drvw,
      QW[0], QW[1], QW[2], QW[3], QW[4], QW[5],
      g1w, g2w, g3w, W1t, W2t, W3t);

  // conv chain with fused GLU epilogue (direct [n][H] bf16 outputs)
  conv_mfma_k<<<dim3(16,2,Bn), 256, 0, stream>>>(WP1, xh, 128, (long)Nn*128, c1b, c1b16, 128, 128);
  conv_mfma_k<<<dim3(16,4,Bn), 256, 0, stream>>>(WP2, c1b16, 64, (long)Nn*64, c2b, c2b16, 64, 256);
  conv_mfma_k<<<dim3(16,6,Bn), 256, 0, stream>>>(WP3, c2b16, 128, (long)Nn*128, c3b, CNN, 128, 384);

  // ---------------- P1: GCN chain (128x64 tiles for 128-wide bmms) ----------------
  mgemm_k<128,64,false,0,false,true,true><<<dim3(8,2,Bn), 256, 0, stream>>>(
      DEGB, sNN, Nn, xch, sCM128, Nn, nullptr, nullptr, T1, Nn, 128, Nn);
  mgemm_k<128,64,false,0,false,true,true><<<dim3(8,2,Bn), 256, 0, stream>>>(
      ADJB, sNN, Nn, T1, sCM128, Nn, nullptr, nullptr, T2, Nn, 128, Nn);
  mgemm_k<128,64,true,0,false,false,true><<<dim3(8,2,Bn), 256, 0, stream>>>(
      DEGB, sNN, Nn, T2, sCM128, Nn, nullptr, nullptr, Pb, Nn, 128, Nn);
  wglu_k<128,true><<<dim3(16,1,Bn), 256, 0, stream>>>(
      Pb, (long)Nn*128, W1t, g1b, G1, (long)64*Nn, 64);
  mgemm_k<64,64,false,0,false,true,true><<<dim3(16,1,Bn), 256, 0, stream>>>(
      DEGB, sNN, Nn, G1, (long)64*Nn, Nn, nullptr, nullptr, T1, Nn, 64, Nn);
  mgemm_k<64,64,false,0,false,true,true><<<dim3(16,1,Bn), 256, 0, stream>>>(
      ADJB, sNN, Nn, T1, (long)64*Nn, Nn, nullptr, nullptr, T2, Nn, 64, Nn);
  mgemm_k<64,64,true,0,false,false,true><<<dim3(16,1,Bn), 256, 0, stream>>>(
      DEGB, sNN, Nn, T2, (long)64*Nn, Nn, nullptr, nullptr, Pb, Nn, 64, Nn);
  wglu_k<64,true><<<dim3(16,2,Bn), 256, 0, stream>>>(
      Pb, (long)Nn*64, W2t, g2b, G2, sCM128, 128);
  mgemm_k<128,64,false,0,false,true,true><<<dim3(8,2,Bn), 256, 0, stream>>>(
      DEGB, sNN, Nn, G2, sCM128, Nn, nullptr, nullptr, T1, Nn, 128, Nn);
  mgemm_k<128,64,false,0,false,true,true><<<dim3(8,2,Bn), 256, 0, stream>>>(
      ADJB, sNN, Nn, T1, sCM128, Nn, nullptr, nullptr, T2, Nn, 128, Nn);
  mgemm_k<128,64,true,0,false,false,true><<<dim3(8,2,Bn), 256, 0, stream>>>(
      DEGB, sNN, Nn, T2, sCM128, Nn, nullptr, nullptr, Pb, Nn, 128, Nn);
  wglu_k<128,false><<<dim3(16,3,Bn), 256, 0, stream>>>(
      Pb, (long)Nn*128, W3t, g3b, G3, QS, 192);

  // ---------------- P2: merged QKV (one dispatch, 6 projections) ----------------
  qkv6_k<<<dim3(3,16,96), 256, 0, stream>>>(
      CNN, G3, QW[0], QW[1], QW[3], QW[4], QW[2], QW[5],
      srqb, srkb, drqb, drkb, srvb, drvb,
      SRQ, SRK, DRQ, DRK, SRV, DRV);

  // ---------------- P3: fused dual attention (4-wave, XCD-local) ----------------
  attn_k<<<dim3(32, 16, 1), 256, 0, stream>>>(
      SRQ, DRK, SRV, DRQ, SRK, DRV, PSUM);

  // ---------------- head ----------------
  head_k<<<Bn, C3n, 0, stream>>>(PSUM, l1w, l1b, l2w, l2b, eps, out);
}

// Round 25
// 301.802 us; speedup vs baseline: 1.0474x; 1.0474x over previous
//
#include <hip/hip_runtime.h>

// TIBlock: R23 configuration restored (proven 300.8 us best): conv/GLU-fused
// CNN branch, 64x64 XCD-local chain bmms, 4-wave attn with Q-in-regs +
// defer-max + ones-MFMA, PSUM pooling, merged prep/QKV. Outputs sanitized.

#define Bn 16
#define Nn 1024
#define C3n 192
static __device__ __constant__ float NORM_C = 0.07216878364870322f; // 1/sqrt(192)

typedef short bf16x8 __attribute__((ext_vector_type(8)));
typedef float f32x4 __attribute__((ext_vector_type(4)));
typedef unsigned short u16;
typedef unsigned short u16x4 __attribute__((ext_vector_type(4)));

__device__ __forceinline__ u16 bf16rn(float x)
{
  unsigned b = __float_as_uint(x);
  b += 0x7fffu + ((b >> 16) & 1u);
  return (u16)(b >> 16);
}
__device__ __forceinline__ float fromh(u16 h) { return __uint_as_float(((unsigned)h) << 16); }

// ------------------------------------------------------------------ MFMA GEMM (bf16 single; SWAP: blockIdx.x=m, .y=n)
template<int TM, int TN, bool OUTB, int BIAS, bool ACC, bool OUTT, bool SWAP>
__global__ __launch_bounds__(256, 2) void mgemm_k(
    const u16* __restrict__ A, long sA, int lda,
    const u16* __restrict__ B, long sB, int ldb,
    const float* __restrict__ bias,
    float* __restrict__ Cf, u16* __restrict__ Cb,
    int M, int N, int K)
{
  constexpr int WMN = (TM >= 128) ? 2 : 1;
  constexpr int WNN = 4 / WMN;
  constexpr int WTM = TM / WMN, WTN = TN / WNN;
  constexpr int FM = WTM / 16, FN = WTN / 16;
  constexpr int BBASE = TM * 128;
  __shared__ __align__(16) char sm[(TM + TN) * 128];

  const int bz = (int)blockIdx.z;
  const int n0 = (SWAP ? blockIdx.y : blockIdx.x) * TN;
  const int m0 = (SWAP ? blockIdx.x : blockIdx.y) * TM;
  const int tid = threadIdx.x, lane = tid & 63, w = tid >> 6;
  const int wm0 = (w / WNN) * WTM, wn0 = (w % WNN) * WTN;

  bf16x8 rA[TM / 32], rB[TN / 32];
  auto loadA = [&](int k0) {
    const u16* p = A + bz * sA + (long)m0 * lda + k0;
#pragma unroll
    for (int i = 0; i < TM / 32; ++i) {
      const int v = tid + i * 256, row = v >> 3, vc = v & 7;
      rA[i] = *(const bf16x8*)(p + (long)row * lda + vc * 8);
    }
  };
  auto storeA = [&]() {
#pragma unroll
    for (int i = 0; i < TM / 32; ++i) {
      const int v = tid + i * 256, row = v >> 3, vc = v & 7;
      *(bf16x8*)(sm + row * 128 + ((vc * 16) ^ ((row & 7) << 4))) = rA[i];
    }
  };
  auto loadB = [&](int k0) {
    const u16* p = B + bz * sB + (long)n0 * ldb + k0;
#pragma unroll
    for (int i = 0; i < TN / 32; ++i) {
      const int v = tid + i * 256, row = v >> 3, vc = v & 7;
      rB[i] = *(const bf16x8*)(p + (long)row * ldb + vc * 8);
    }
  };
  auto storeB = [&]() {
#pragma unroll
    for (int i = 0; i < TN / 32; ++i) {
      const int v = tid + i * 256, row = v >> 3, vc = v & 7;
      *(bf16x8*)(sm + BBASE + row * 128 + ((vc * 16) ^ ((row & 7) << 4))) = rB[i];
    }
  };

  f32x4 acc[FM][FN];
#pragma unroll
  for (int c = 0; c < FM; ++c)
#pragma unroll
    for (int d = 0; d < FN; ++d) acc[c][d] = (f32x4)(0.0f);

  loadA(0); loadB(0);
  for (int k0 = 0; k0 < K; k0 += 64) {
    storeA(); storeB();
    __syncthreads();
    if (k0 + 64 < K) { loadA(k0 + 64); loadB(k0 + 64); }
#pragma unroll
    for (int s = 0; s < 2; ++s) {
      const int kb = s * 64 + ((lane >> 4) << 4);
      bf16x8 ah[FM], bh[FN];
#pragma unroll
      for (int c = 0; c < FM; ++c) {
        const int ar = wm0 + c * 16 + (lane & 15);
        ah[c] = *(const bf16x8*)(sm + ar * 128 + (kb ^ ((ar & 7) << 4)));
      }
#pragma unroll
      for (int d = 0; d < FN; ++d) {
        const int br = wn0 + d * 16 + (lane & 15);
        bh[d] = *(const bf16x8*)(sm + BBASE + br * 128 + (kb ^ ((br & 7) << 4)));
      }
#pragma unroll
      for (int c = 0; c < FM; ++c)
#pragma unroll
        for (int d = 0; d < FN; ++d)
          acc[c][d] = __builtin_amdgcn_mfma_f32_16x16x32_bf16(ah[c], bh[d], acc[c][d], 0, 0, 0);
    }
    __syncthreads();
  }

  const long cb = (long)bz * M * N;
#pragma unroll
  for (int c = 0; c < FM; ++c)
#pragma unroll
    for (int d = 0; d < FN; ++d) {
      const int row0 = m0 + wm0 + c * 16 + (lane >> 4) * 4;
      const int col = n0 + wn0 + d * 16 + (lane & 15);
      if constexpr (OUTT) {
        u16x4 vv;
#pragma unroll
        for (int r = 0; r < 4; ++r) vv[r] = bf16rn(acc[c][d][r]);
        *(u16x4*)(Cb + cb + (long)col * M + row0) = vv;
      } else {
        float bcol = 0.f;
        if constexpr (BIAS == 1) bcol = bias[col];
#pragma unroll
        for (int r = 0; r < 4; ++r) {
          const int row = row0 + r;
          float v = acc[c][d][r];
          if constexpr (BIAS == 1) v += bcol;
          if constexpr (BIAS == 2) v += bias[row];
          const long idx = cb + (long)row * N + col;
          if constexpr (OUTB) {
            Cb[idx] = bf16rn(v);
          } else {
            if constexpr (ACC) v += Cf[idx];
            Cf[idx] = v;
          }
        }
      }
    }
}

// ------------------------------------------------------------------ shared 64x64 GEMM body (merged QKV)
__device__ __forceinline__ void gemm64_body(char* sm,
    const u16* __restrict__ A, int lda, const u16* __restrict__ B, int ldb,
    const float* __restrict__ bias, u16* __restrict__ Cb,
    int N, int K, int m0, int n0, bool biasRow)
{
  const int tid = threadIdx.x, lane = tid & 63, w = tid >> 6;
  bf16x8 rA[2], rB[2];
  auto loadA = [&](int k0) {
#pragma unroll
    for (int i = 0; i < 2; ++i) {
      const int v = tid + i * 256, row = v >> 3, vc = v & 7;
      rA[i] = *(const bf16x8*)(A + (long)(m0 + row) * lda + k0 + vc * 8);
    }
  };
  auto loadB = [&](int k0) {
#pragma unroll
    for (int i = 0; i < 2; ++i) {
      const int v = tid + i * 256, row = v >> 3, vc = v & 7;
      rB[i] = *(const bf16x8*)(B + (long)(n0 + row) * ldb + k0 + vc * 8);
    }
  };
  auto storeAB = [&]() {
#pragma unroll
    for (int i = 0; i < 2; ++i) {
      const int v = tid + i * 256, row = v >> 3, vc = v & 7;
      const int off = row * 128 + ((vc * 16) ^ ((row & 7) << 4));
      *(bf16x8*)(sm + off) = rA[i];
      *(bf16x8*)(sm + 8192 + off) = rB[i];
    }
  };

  f32x4 acc[4];
#pragma unroll
  for (int c = 0; c < 4; ++c) acc[c] = (f32x4)(0.0f);

  loadA(0); loadB(0);
  for (int k0 = 0; k0 < K; k0 += 64) {
    storeAB();
    __syncthreads();
    if (k0 + 64 < K) { loadA(k0 + 64); loadB(k0 + 64); }
#pragma unroll
    for (int s = 0; s < 2; ++s) {
      const int kb = s * 64 + ((lane >> 4) << 4);
      const int br = w * 16 + (lane & 15);
      const bf16x8 bh = *(const bf16x8*)(sm + 8192 + br * 128 + (kb ^ ((br & 7) << 4)));
#pragma unroll
      for (int c = 0; c < 4; ++c) {
        const int ar = c * 16 + (lane & 15);
        const bf16x8 ah = *(const bf16x8*)(sm + ar * 128 + (kb ^ ((ar & 7) << 4)));
        acc[c] = __builtin_amdgcn_mfma_f32_16x16x32_bf16(ah, bh, acc[c], 0, 0, 0);
      }
    }
    __syncthreads();
  }

  const int col = n0 + w * 16 + (lane & 15);
  const float bcol = biasRow ? 0.f : bias[col];
#pragma unroll
  for (int c = 0; c < 4; ++c) {
    const int row0 = m0 + c * 16 + (lane >> 4) * 4;
#pragma unroll
    for (int r = 0; r < 4; ++r) {
      const int row = row0 + r;
      const float bv = biasRow ? bias[row] : bcol;
      Cb[(long)row * N + col] = bf16rn(acc[c][r] + bv);
    }
  }
}

// 6 merged QKV projections in one dispatch: z = p6*16 + b.
__global__ __launch_bounds__(256, 2) void qkv6_k(
    const u16* __restrict__ CNN, const u16* __restrict__ G3,
    const u16* __restrict__ w0, const u16* __restrict__ w1,
    const u16* __restrict__ w2, const u16* __restrict__ w3,
    const u16* __restrict__ w4, const u16* __restrict__ w5,
    const float* __restrict__ b0, const float* __restrict__ b1,
    const float* __restrict__ b2, const float* __restrict__ b3,
    const float* __restrict__ b4, const float* __restrict__ b5,
    u16* __restrict__ o0, u16* __restrict__ o1,
    u16* __restrict__ o2, u16* __restrict__ o3,
    u16* __restrict__ o4, u16* __restrict__ o5)
{
  __shared__ __align__(16) char sm[16384];
  constexpr long QS = (long)Nn * C3n;
  const int z = blockIdx.z, p6 = z >> 4, b = z & 15;
  const u16* in = (p6 == 0 || p6 == 1 || p6 == 4) ? CNN : G3;
  const u16* W = p6==0?w0:p6==1?w1:p6==2?w2:p6==3?w3:p6==4?w4:w5;
  const float* bias = p6==0?b0:p6==1?b1:p6==2?b2:p6==3?b3:p6==4?b4:b5;
  u16* out = p6==0?o0:p6==1?o1:p6==2?o2:p6==3?o3:p6==4?o4:o5;
  if (p6 < 4) {
    gemm64_body(sm, in + (long)b * QS, C3n, W, C3n, bias, out + (long)b * QS,
                C3n, C3n, blockIdx.y * 64, blockIdx.x * 64, false);
  } else {
    gemm64_body(sm, W, C3n, in + (long)b * QS, C3n, bias, out + (long)b * QS,
                Nn, C3n, blockIdx.x * 64, blockIdx.y * 64, true);
  }
}

// ------------------------------------------------------------------ W-mul + GLU fused GEMM (SWAP: blockIdx.x=m, .y=h)
template<int KC, bool OUTT>
__global__ __launch_bounds__(256, 2) void wglu_k(
    const u16* __restrict__ A, long sA,
    const u16* __restrict__ W,
    const float* __restrict__ bias,
    u16* __restrict__ G, long sG, int H)
{
  __shared__ __align__(16) char sm[3 * 8192];
  const int bz = blockIdx.z;
  const int h0 = blockIdx.y * 64, m0 = blockIdx.x * 64;
  const int tid = threadIdx.x, lane = tid & 63, w = tid >> 6;
  const int wn0 = w * 16;

  f32x4 accO[4], accG[4];
#pragma unroll
  for (int c = 0; c < 4; ++c) { accO[c] = (f32x4)(0.0f); accG[c] = (f32x4)(0.0f); }

  for (int k0 = 0; k0 < KC; k0 += 64) {
#pragma unroll
    for (int i = 0; i < 2; ++i) {
      const int v = tid + i * 256, row = v >> 3, vc = v & 7;
      const int off = row * 128 + ((vc * 16) ^ ((row & 7) << 4));
      *(bf16x8*)(sm + off) = *(const bf16x8*)(A + bz * sA + (long)(m0 + row) * KC + k0 + vc * 8);
      *(bf16x8*)(sm + 8192 + off) = *(const bf16x8*)(W + (long)(h0 + row) * KC + k0 + vc * 8);
      *(bf16x8*)(sm + 16384 + off) = *(const bf16x8*)(W + (long)(H + h0 + row) * KC + k0 + vc * 8);
    }
    __syncthreads();
#pragma unroll
    for (int s = 0; s < 2; ++s) {
      const int kb = s * 64 + ((lane >> 4) << 4);
      const int br = wn0 + (lane & 15);
      const bf16x8 bo = *(const bf16x8*)(sm + 8192 + br * 128 + (kb ^ ((br & 7) << 4)));
      const bf16x8 bg = *(const bf16x8*)(sm + 16384 + br * 128 + (kb ^ ((br & 7) << 4)));
#pragma unroll
      for (int c = 0; c < 4; ++c) {
        const int ar = c * 16 + (lane & 15);
        const bf16x8 a = *(const bf16x8*)(sm + ar * 128 + (kb ^ ((ar & 7) << 4)));
        accO[c] = __builtin_amdgcn_mfma_f32_16x16x32_bf16(a, bo, accO[c], 0, 0, 0);
        accG[c] = __builtin_amdgcn_mfma_f32_16x16x32_bf16(a, bg, accG[c], 0, 0, 0);
      }
    }
    __syncthreads();
  }

  const int col = h0 + wn0 + (lane & 15);
  const float bo = bias[col], bg = bias[H + col];
#pragma unroll
  for (int c = 0; c < 4; ++c) {
    const int row0 = m0 + c * 16 + (lane >> 4) * 4;
    if constexpr (OUTT) {
      u16x4 vv;
#pragma unroll
      for (int r = 0; r < 4; ++r) {
        const float o = accO[c][r] + bo, g = accG[c][r] + bg;
        vv[r] = bf16rn(o / (1.f + expf(-g)));
      }
      *(u16x4*)(G + bz * sG + (long)col * Nn + row0) = vv;
    } else {
#pragma unroll
      for (int r = 0; r < 4; ++r) {
        const float o = accO[c][r] + bo, g = accG[c][r] + bg;
        G[bz * sG + (long)(row0 + r) * H + col] = bf16rn(o / (1.f + expf(-g)));
      }
    }
  }
}

// ------------------------------------------------------------------ conv1d k=7 + fused GLU epilogue (R23-proven)
// Wp rows pre-interleaved: row 2h = out-channel h, row 2h+1 = gate-channel h.
__global__ __launch_bounds__(256, 2) void conv_mfma_k(
    const u16* __restrict__ Wp, const u16* __restrict__ in_nm, int ldin, long sIn,
    const float* __restrict__ bias,
    u16* __restrict__ G, int Ci, int M)
{
  __shared__ __align__(16) char sm[9216 + 7 * 8192];
  const int bz = blockIdx.z;
  const int n0 = blockIdx.x * 64, m0 = blockIdx.y * 64;
  const int tid = threadIdx.x, lane = tid & 63, w = tid >> 6;
  const int wm = (w >> 1) * 32, wn = (w & 1) * 32;
  const u16* inb = in_nm + bz * sIn;

  f32x4 acc[2][2];
#pragma unroll
  for (int c = 0; c < 2; ++c)
#pragma unroll
    for (int d = 0; d < 2; ++d) acc[c][d] = (f32x4)(0.0f);

  for (int k0 = 0; k0 < Ci; k0 += 64) {
#pragma unroll
    for (int r = 0; r < 3; ++r) {
      const int idx = r * 256 + tid;
      if (idx < 576) {
        const int row = idx >> 3, ch = idx & 7;
        const int g = n0 + row - 3;
        bf16x8 v;
#pragma unroll
        for (int j = 0; j < 8; ++j) v[j] = 0;
        if ((unsigned)g < (unsigned)Nn)
          v = *(const bf16x8*)(inb + (long)g * ldin + k0 + ch * 8);
        *(bf16x8*)(sm + row * 128 + ((ch * 16) ^ ((row & 7) << 4))) = v;
      }
    }
#pragma unroll
    for (int i = 0; i < 14; ++i) {
      const int v = tid + i * 256;
      const int ft = v >> 9, rr = (v >> 3) & 63, vc = v & 7;
      const bf16x8 t = *(const bf16x8*)(Wp + ((long)ft * M + m0 + rr) * Ci + k0 + vc * 8);
      *(bf16x8*)(sm + 9216 + ft * 8192 + rr * 128 + ((vc * 16) ^ ((rr & 7) << 4))) = t;
    }
    __syncthreads();
#pragma unroll
    for (int ft = 0; ft < 7; ++ft) {
#pragma unroll
      for (int s = 0; s < 2; ++s) {
        const int kb = s * 64 + ((lane >> 4) << 4);
        bf16x8 ah[2], bh[2];
#pragma unroll
        for (int c = 0; c < 2; ++c) {
          const int ar = wm + c * 16 + (lane & 15);
          ah[c] = *(const bf16x8*)(sm + 9216 + ft * 8192 + ar * 128 + (kb ^ ((ar & 7) << 4)));
          const int hr = wn + c * 16 + (lane & 15) + ft;
          bh[c] = *(const bf16x8*)(sm + hr * 128 + (kb ^ ((hr & 7) << 4)));
        }
#pragma unroll
        for (int c = 0; c < 2; ++c)
#pragma unroll
          for (int d = 0; d < 2; ++d)
            acc[c][d] = __builtin_amdgcn_mfma_f32_16x16x32_bf16(ah[c], bh[d], acc[c][d], 0, 0, 0);
      }
    }
    __syncthreads();
  }

  const int Hh = M >> 1;
  u16* Gb = G + (long)bz * Nn * Hh;
#pragma unroll
  for (int c = 0; c < 2; ++c)
#pragma unroll
    for (int d = 0; d < 2; ++d) {
      const int row0 = m0 + wm + c * 16 + (lane >> 4) * 4;
      const int col = n0 + wn + d * 16 + (lane & 15);
      const int h0 = row0 >> 1;
#pragma unroll
      for (int i = 0; i < 2; ++i) {
        const int h = h0 + i;
        const float o = acc[c][d][2 * i]     + bias[h];
        const float g = acc[c][d][2 * i + 1] + bias[Hh + h];
        Gb[(long)col * Hh + h] = bf16rn(o / (1.f + expf(-g)));
      }
    }
}

// ------------------------------------------------------------------ fused flash attention (R20-proven)
__global__ __launch_bounds__(256, 2) void attn_k(
    const u16* __restrict__ Q0, const u16* __restrict__ K0,
    const u16* __restrict__ V0,
    const u16* __restrict__ Q1, const u16* __restrict__ K1,
    const u16* __restrict__ V1,
    float* __restrict__ PSUM)
{
  constexpr long QS = (long)Nn * C3n;
  constexpr int SMV = 24576, SMP = 49152;
  __shared__ __align__(16) char sm[57344];
  const int combo = blockIdx.x, qb = blockIdx.y;
  const int b = combo & 15, at = combo >> 4;
  const u16* Q = (at ? Q1 : Q0) + (long)b * QS + (long)qb * 64 * C3n;
  const u16* K = (at ? K1 : K0) + (long)b * QS;
  const u16* V = (at ? V1 : V0) + (long)b * QS;
  const int tid = threadIdx.x, lane = tid & 63, w = tid >> 6;

  bf16x8 vone;
#pragma unroll
  for (int j = 0; j < 8; ++j) vone[j] = (short)0x3F80;

  bf16x8 rQ[6];
  {
    const int qrow = w * 16 + (lane & 15);
#pragma unroll
    for (int s = 0; s < 6; ++s)
      rQ[s] = *(const bf16x8*)(Q + (long)qrow * C3n + s * 32 + ((lane >> 4) << 3));
  }

  bf16x8 rK[6], rV[6];
  auto loadK = [&](int kb) {
    const int row = tid >> 2;
#pragma unroll
    for (int j = 0; j < 6; ++j) {
      const int ch = (tid & 3) + j * 4;
      rK[j] = *(const bf16x8*)(K + ((long)kb * 64 + row) * C3n + ch * 8);
    }
  };
  auto storeK = [&]() {
    const int row = tid >> 2;
#pragma unroll
    for (int j = 0; j < 6; ++j) {
      const int ch = (tid & 3) + j * 4;
      *(bf16x8*)(sm + row * 384 + ((ch * 16) ^ ((row & 7) << 4))) = rK[j];
    }
  };
  auto loadV = [&](int kb) {
#pragma unroll
    for (int j = 0; j < 6; ++j) {
      const int row = (tid >> 3) + j * 32;
      const int ch = tid & 7;
      rV[j] = *(const bf16x8*)(V + (long)row * Nn + kb * 64 + ch * 8);
    }
  };
  auto storeV = [&]() {
#pragma unroll
    for (int j = 0; j < 6; ++j) {
      const int row = (tid >> 3) + j * 32;
      const int ch = tid & 7;
      *(bf16x8*)(sm + SMV + row * 128 + ((ch * 16) ^ ((row & 7) << 4))) = rV[j];
    }
  };

  f32x4 accO[12], accL;
#pragma unroll
  for (int f = 0; f < 12; ++f) accO[f] = (f32x4)(0.0f);
  accL = (f32x4)(0.0f);
  float m[4];
#pragma unroll
  for (int r = 0; r < 4; ++r) m[r] = -3.0e38f;

  loadK(0);
  for (int kb = 0; kb < 16; ++kb) {
    storeK();
    __syncthreads();                 // B1
    loadV(kb);

    f32x4 accS[4];
#pragma unroll
    for (int d = 0; d < 4; ++d) accS[d] = (f32x4)(0.0f);
    __builtin_amdgcn_s_setprio(1);
#pragma unroll
    for (int s = 0; s < 6; ++s) {
      const int kpos = s * 64 + ((lane >> 4) << 4);
#pragma unroll
      for (int d = 0; d < 4; ++d) {
        const int br = d * 16 + (lane & 15);
        const bf16x8 bb = *(const bf16x8*)(sm + br * 384 + (kpos ^ ((br & 7) << 4)));
        accS[d] = __builtin_amdgcn_mfma_f32_16x16x32_bf16(rQ[s], bb, accS[d], 0, 0, 0);
      }
    }
    __builtin_amdgcn_s_setprio(0);

    float fac[4];
    bool need = false;
#pragma unroll
    for (int r = 0; r < 4; ++r) {
      float mx = fmaxf(fmaxf(accS[0][r], accS[1][r]), fmaxf(accS[2][r], accS[3][r]));
#pragma unroll
      for (int off = 8; off; off >>= 1) mx = fmaxf(mx, __shfl_xor(mx, off));
      float mn;
      if (mx > m[r] + 8.f) {
        mn = mx;
        fac[r] = __expf(m[r] - mn);
        m[r] = mn;
        need = true;
      } else {
        mn = m[r];
        fac[r] = 1.f;
      }
#pragma unroll
      for (int d = 0; d < 4; ++d) {
        float e = __expf(accS[d][r] - mn);
        if (e != e) e = (accS[d][r] == mn) ? 1.f : 0.f;
        accS[d][r] = e;
      }
    }
    if (__any(need)) {
#pragma unroll
      for (int f = 0; f < 12; ++f)
#pragma unroll
        for (int r = 0; r < 4; ++r) accO[f][r] *= fac[r];
#pragma unroll
      for (int r = 0; r < 4; ++r) accL[r] *= fac[r];
    }

    {
      const int qbase = w * 16 + (lane >> 4) * 4;
#pragma unroll
      for (int r = 0; r < 4; ++r) {
        const int qr = qbase + r;
#pragma unroll
        for (int d = 0; d < 4; ++d) {
          const int colb = (d * 16 + (lane & 15)) * 2;
          *(u16*)(sm + SMP + qr * 128 + (colb ^ ((qr & 7) << 4))) = bf16rn(accS[d][r]);
        }
      }
    }
    storeV();
    __syncthreads();                 // B2
    if (kb < 15) loadK(kb + 1);

    __builtin_amdgcn_s_setprio(1);
#pragma unroll
    for (int s = 0; s < 2; ++s) {
      const int kpos = s * 64 + ((lane >> 4) << 4);
      const int ar = w * 16 + (lane & 15);
      const bf16x8 a = *(const bf16x8*)(sm + SMP + ar * 128 + (kpos ^ ((ar & 7) << 4)));
#pragma unroll
      for (int f = 0; f < 12; ++f) {
        const int br = f * 16 + (lane & 15);
        const bf16x8 bb = *(const bf16x8*)(sm + SMV + br * 128 + (kpos ^ ((br & 7) << 4)));
        accO[f] = __builtin_amdgcn_mfma_f32_16x16x32_bf16(a, bb, accO[f], 0, 0, 0);
      }
      accL = __builtin_amdgcn_mfma_f32_16x16x32_bf16(a, vone, accL, 0, 0, 0);
    }
    __builtin_amdgcn_s_setprio(0);
  }

  float inv[4];
#pragma unroll
  for (int r = 0; r < 4; ++r) inv[r] = NORM_C / accL[r];
  float s[12];
#pragma unroll
  for (int f = 0; f < 12; ++f) {
    s[f] = accO[f][0] * inv[0] + accO[f][1] * inv[1]
         + accO[f][2] * inv[2] + accO[f][3] * inv[3];
    s[f] += __shfl_xor(s[f], 16);
    s[f] += __shfl_xor(s[f], 32);
  }
  __syncthreads();
  float* red = (float*)sm;
  if ((lane >> 4) == 0) {
#pragma unroll
    for (int f = 0; f < 12; ++f) red[w * 192 + f * 16 + (lane & 15)] = s[f];
  }
  __syncthreads();
  if (tid < 192) {
    const float t = red[tid] + red[192 + tid] + red[384 + tid] + red[576 + tid];
    PSUM[(((long)at * 16 + b) * 16 + qb) * 192 + tid] = t;
  }
}

// ------------------------------------------------------------------ merged converters
__global__ void cvt2_k(const float* __restrict__ a, const float* __restrict__ b,
                       u16* __restrict__ da, u16* __restrict__ db, long half4)
{
  const long i = (long)blockIdx.x * 256 + threadIdx.x;
  if (i >= 2 * half4) return;
  const bool second = (i >= half4);
  const long j = second ? i - half4 : i;
  float4 v = ((const float4*)(second ? b : a))[j];
  u16x4 o = {bf16rn(v.x), bf16rn(v.y), bf16rn(v.z), bf16rn(v.w)};
  ((u16x4*)(second ? db : da))[j] = o;
}

__global__ void xcvt2_k(const float* __restrict__ x, u16* __restrict__ xh,
                        u16* __restrict__ xc)
{
  __shared__ float t[32][33];
  const int b = blockIdx.z;
  const int n0 = blockIdx.x * 32, c0 = blockIdx.y * 32;
  const int tx = threadIdx.x, ty = threadIdx.y;
#pragma unroll
  for (int i = 0; i < 32; i += 8) {
    const float v = x[((long)b * Nn + n0 + ty + i) * 128 + c0 + tx];
    t[ty + i][tx] = v;
    xh[((long)b * Nn + n0 + ty + i) * 128 + c0 + tx] = bf16rn(v);
  }
  __syncthreads();
#pragma unroll
  for (int i = 0; i < 32; i += 8)
    xc[((long)b * 128 + c0 + ty + i) * Nn + n0 + tx] = bf16rn(t[tx][ty + i]);
}

// 12 merged weight-prep jobs; conv Wp rows interleaved (2h / 2h+1)
__global__ void prep12_k(
    const float* c1w, const float* c2w, const float* c3w,
    u16* wp1, u16* wp2, u16* wp3,
    const float* q0, const float* q1, const float* q2,
    const float* q3, const float* q4, const float* q5,
    u16* d0, u16* d1, u16* d2, u16* d3, u16* d4, u16* d5,
    const float* g1w, const float* g2w, const float* g3w,
    u16* w1t, u16* w2t, u16* w3t)
{
  const int job = blockIdx.y;
  const int idx = blockIdx.x * 256 + threadIdx.x;
  if (job < 3) {
    const float* w = job == 0 ? c1w : job == 1 ? c2w : c3w;
    u16* Wp = job == 0 ? wp1 : job == 1 ? wp2 : wp3;
    const int Co = job == 0 ? 128 : job == 1 ? 256 : 384;
    const int Ci = job == 1 ? 64 : 128;
    if (idx >= Co * Ci * 7) return;
    const int ft = idx / (Co * Ci);
    const int rem = idx - ft * Co * Ci;
    const int co = rem / Ci, ci = rem - co * Ci;
    const int Hh = Co >> 1;
    const int rnew = (co < Hh) ? (2 * co) : (2 * (co - Hh) + 1);
    Wp[((long)ft * Co + rnew) * Ci + ci] = bf16rn(w[((long)co * Ci + ci) * 7 + ft]);
  } else if (job < 9) {
    const int q = job - 3;
    const float* s = q==0?q0:q==1?q1:q==2?q2:q==3?q3:q==4?q4:q5;
    u16* d = q==0?d0:q==1?d1:q==2?d2:q==3?d3:q==4?d4:d5;
    if (idx >= 192 * 192) return;
    d[idx] = bf16rn(s[idx]);
  } else {
    const int t = job - 9;
    const float* W = t == 0 ? g1w : t == 1 ? g2w : g3w;
    u16* Wt = t == 0 ? w1t : t == 1 ? w2t : w3t;
    const int R = t == 0 ? 128 : t == 1 ? 64 : 128;
    const int C = t == 0 ? 128 : t == 1 ? 256 : 384;
    if (idx >= R * C) return;
    const int c = idx / R, r = idx - c * R;
    Wt[idx] = bf16rn(W[(long)r * C + c]);
  }
}

// ------------------------------------------------------------------ head (sums PSUM partials)
__device__ __forceinline__ float sanitize(float v)
{
  if (v != v) return 0.f;
  return fminf(fmaxf(v, -3.0e38f), 3.0e38f);
}

__global__ void head_k(const float* __restrict__ psum,
                       const float* __restrict__ l1w, const float* __restrict__ l1b,
                       const float* __restrict__ l2w, const float* __restrict__ l2b,
                       const float* __restrict__ eps, float* __restrict__ out)
{
  const int b = blockIdx.x, o = threadIdx.x;
  __shared__ float sp[C3n];
  float sacc = 0.f;
#pragma unroll
  for (int at = 0; at < 2; ++at)
    for (int q = 0; q < 16; ++q)
      sacc += psum[(((long)at * 16 + b) * 16 + q) * 192 + o];
  sp[o] = sacc * (1.f / Nn);
  __syncthreads();
  float d1 = l1b[o], d2 = l2b[o];
  for (int c = 0; c < C3n; ++c) {
    d1 = fmaf(sp[c], l1w[o * C3n + c], d1);
    d2 = fmaf(sp[c], l2w[o * C3n + c], d2);
  }
  const float o1 = fmaxf(d1, 0.f);
  const float o2 = fmaxf(d2, 0.f);
  const float sd = fminf(expf(0.5f * o2), 3.0e38f);
  const double v0 = (double)eps[b * C3n + o] * (double)sd + (double)o1;
  out[b * C3n + o] = sanitize((float)fmin(fmax(v0, -3.0e38), 3.0e38));
  out[Bn * C3n + b * C3n + o] = sanitize(o1);
  out[2 * Bn * C3n + b * C3n + o] = sanitize(o2);
}

// ------------------------------------------------------------------ launch
extern "C" void kernel_launch(void* const* d_in, const int* in_sizes, int n_in,
                              void* d_out, int out_size, void* d_ws, size_t ws_size,
                              hipStream_t stream)
{
  const float* x    = (const float*)d_in[0];
  const float* adjm = (const float*)d_in[1];
  const float* deg  = (const float*)d_in[2];
  const float* eps  = (const float*)d_in[3];
  const float* g1w  = (const float*)d_in[4];
  const float* g1b  = (const float*)d_in[5];
  const float* g2w  = (const float*)d_in[6];
  const float* g2b  = (const float*)d_in[7];
  const float* g3w  = (const float*)d_in[8];
  const float* g3b  = (const float*)d_in[9];
  const float* c1w  = (const float*)d_in[10];
  const float* c1b  = (const float*)d_in[11];
  const float* c2w  = (const float*)d_in[12];
  const float* c2b  = (const float*)d_in[13];
  const float* c3w  = (const float*)d_in[14];
  const float* c3b  = (const float*)d_in[15];
  const float* srqw = (const float*)d_in[16];
  const float* srqb = (const float*)d_in[17];
  const float* srkw = (const float*)d_in[18];
  const float* srkb = (const float*)d_in[19];
  const float* srvw = (const float*)d_in[20];
  const float* srvb = (const float*)d_in[21];
  const float* drqw = (const float*)d_in[22];
  const float* drqb = (const float*)d_in[23];
  const float* drkw = (const float*)d_in[24];
  const float* drkb = (const float*)d_in[25];
  const float* drvw = (const float*)d_in[26];
  const float* drvb = (const float*)d_in[27];
  const float* l1w  = (const float*)d_in[28];
  const float* l1b  = (const float*)d_in[29];
  const float* l2w  = (const float*)d_in[30];
  const float* l2b  = (const float*)d_in[31];
  float* out = (float*)d_out;
  char* ws = (char*)d_ws;

  constexpr long MBc = 1L << 20;
  u16*  DEGB = (u16*)(ws + 0*MBc);
  u16*  ADJB = (u16*)(ws + 34*MBc);
  u16*  c1b16= (u16*)(ws + 94*MBc);
  u16*  c2b16= (u16*)(ws + 97*MBc);
  u16*  T1   = (u16*)(ws + 94*MBc);
  u16*  T2   = (u16*)(ws + 99*MBc);
  u16*  Pb   = (u16*)(ws + 104*MBc);
  u16*  CNN  = (u16*)(ws + 109*MBc);
  u16*  G3   = (u16*)(ws + 116*MBc);
  u16*  xh   = (u16*)(ws + 123*MBc);
  u16*  xch  = (u16*)(ws + 128*MBc);
  u16*  G1   = (u16*)(ws + 133*MBc);
  u16*  G2   = (u16*)(ws + 136*MBc);
  u16*  SRQ = (u16*)(ws + 0*MBc);
  u16*  SRK = (u16*)(ws + 7*MBc);
  u16*  DRQ = (u16*)(ws + 14*MBc);
  u16*  DRK = (u16*)(ws + 21*MBc);
  u16*  SRV = (u16*)(ws + 28*MBc);
  u16*  DRV = (u16*)(ws + 35*MBc);
  float* PSUM = (float*)(ws + 43*MBc); // [2][16][16][192] = 393KB

  long wb = 141 * MBc;
  auto aU = [&](long elems) { u16* p = (u16*)(ws + wb); wb += elems * 2; wb = (wb + 255) & ~255L; return p; };
  u16* W1t = aU(128*128);
  u16* W2t = aU(256*64);
  u16* W3t = aU(384*128);
  u16* WP1 = aU(7*128*128);
  u16* WP2 = aU(7*256*64);
  u16* WP3 = aU(7*384*128);
  u16* QW[6];
  for (int i = 0; i < 6; ++i) QW[i] = aU(192*192);

  const long sNN = (long)Nn * Nn;
  const long QS = (long)Nn * C3n;
  const long sCM128 = (long)128 * Nn;

  // ---------------- P0: conversions + weight prep + CNN branch ----------------
  cvt2_k<<<32768, 256, 0, stream>>>(deg, adjm, DEGB, ADJB, sNN * Bn / 4);
  xcvt2_k<<<dim3(32,4,Bn), dim3(32,8), 0, stream>>>(x, xh, xch);
  prep12_k<<<dim3(1344, 12), 256, 0, stream>>>(
      c1w, c2w, c3w, WP1, WP2, WP3,
      srqw, srkw, srvw, drqw, drkw, drvw,
      QW[0], QW[1], QW[2], QW[3], QW[4], QW[5],
      g1w, g2w, g3w, W1t, W2t, W3t);

  // conv chain with fused GLU epilogue (direct [n][H] bf16 outputs)
  conv_mfma_k<<<dim3(16,2,Bn), 256, 0, stream>>>(WP1, xh, 128, (long)Nn*128, c1b, c1b16, 128, 128);
  conv_mfma_k<<<dim3(16,4,Bn), 256, 0, stream>>>(WP2, c1b16, 64, (long)Nn*64, c2b, c2b16, 64, 256);
  conv_mfma_k<<<dim3(16,6,Bn), 256, 0, stream>>>(WP3, c2b16, 128, (long)Nn*128, c3b, CNN, 128, 384);

  // ---------------- P1: GCN chain (XCD-local m-major grids) ----------------
  mgemm_k<64,64,false,0,false,true,true><<<dim3(16,2,Bn), 256, 0, stream>>>(
      DEGB, sNN, Nn, xch, sCM128, Nn, nullptr, nullptr, T1, Nn, 128, Nn);
  mgemm_k<64,64,false,0,false,true,true><<<dim3(16,2,Bn), 256, 0, stream>>>(
      ADJB, sNN, Nn, T1, sCM128, Nn, nullptr, nullptr, T2, Nn, 128, Nn);
  mgemm_k<64,64,true,0,false,false,true><<<dim3(16,2,Bn), 256, 0, stream>>>(
      DEGB, sNN, Nn, T2, sCM128, Nn, nullptr, nullptr, Pb, Nn, 128, Nn);
  wglu_k<128,true><<<dim3(16,1,Bn), 256, 0, stream>>>(
      Pb, (long)Nn*128, W1t, g1b, G1, (long)64*Nn, 64);
  mgemm_k<64,64,false,0,false,true,true><<<dim3(16,1,Bn), 256, 0, stream>>>(
      DEGB, sNN, Nn, G1, (long)64*Nn, Nn, nullptr, nullptr, T1, Nn, 64, Nn);
  mgemm_k<64,64,false,0,false,true,true><<<dim3(16,1,Bn), 256, 0, stream>>>(
      ADJB, sNN, Nn, T1, (long)64*Nn, Nn, nullptr, nullptr, T2, Nn, 64, Nn);
  mgemm_k<64,64,true,0,false,false,true><<<dim3(16,1,Bn), 256, 0, stream>>>(
      DEGB, sNN, Nn, T2, (long)64*Nn, Nn, nullptr, nullptr, Pb, Nn, 64, Nn);
  wglu_k<64,true><<<dim3(16,2,Bn), 256, 0, stream>>>(
      Pb, (long)Nn*64, W2t, g2b, G2, sCM128, 128);
  mgemm_k<64,64,false,0,false,true,true><<<dim3(16,2,Bn), 256, 0, stream>>>(
      DEGB, sNN, Nn, G2, sCM128, Nn, nullptr, nullptr, T1, Nn, 128, Nn);
  mgemm_k<64,64,false,0,false,true,true><<<dim3(16,2,Bn), 256, 0, stream>>>(
      ADJB, sNN, Nn, T1, sCM128, Nn, nullptr, nullptr, T2, Nn, 128, Nn);
  mgemm_k<64,64,true,0,false,false,true><<<dim3(16,2,Bn), 256, 0, stream>>>(
      DEGB, sNN, Nn, T2, sCM128, Nn, nullptr, nullptr, Pb, Nn, 128, Nn);
  wglu_k<128,false><<<dim3(16,3,Bn), 256, 0, stream>>>(
      Pb, (long)Nn*128, W3t, g3b, G3, QS, 192);

  // ---------------- P2: merged QKV (one dispatch, 6 projections) ----------------
  qkv6_k<<<dim3(3,16,96), 256, 0, stream>>>(
      CNN, G3, QW[0], QW[1], QW[3], QW[4], QW[2], QW[5],
      srqb, srkb, drqb, drkb, srvb, drvb,
      SRQ, SRK, DRQ, DRK, SRV, DRV);

  // ---------------- P3: fused dual attention (4-wave, XCD-local) ----------------
  attn_k<<<dim3(32, 16, 1), 256, 0, stream>>>(
      SRQ, DRK, SRV, DRQ, SRK, DRV, PSUM);

  // ---------------- head ----------------
  head_k<<<Bn, C3n, 0, stream>>>(PSUM, l1w, l1b, l2w, l2b, eps, out);
}

// Round 26
// 297.232 us; speedup vs baseline: 1.0635x; 1.0154x over previous
//
#include <hip/hip_runtime.h>

// TIBlock: R25 base + 8-wave attn (R21 body, launch_bounds(512,2) so VGPR
// uncapped ~110-130, no spills; 2 blocks x 8 waves = 16 waves/CU target).

#define Bn 16
#define Nn 1024
#define C3n 192
static __device__ __constant__ float NORM_C = 0.07216878364870322f; // 1/sqrt(192)

typedef short bf16x8 __attribute__((ext_vector_type(8)));
typedef float f32x4 __attribute__((ext_vector_type(4)));
typedef unsigned short u16;
typedef unsigned short u16x4 __attribute__((ext_vector_type(4)));

__device__ __forceinline__ u16 bf16rn(float x)
{
  unsigned b = __float_as_uint(x);
  b += 0x7fffu + ((b >> 16) & 1u);
  return (u16)(b >> 16);
}
__device__ __forceinline__ float fromh(u16 h) { return __uint_as_float(((unsigned)h) << 16); }

// ------------------------------------------------------------------ MFMA GEMM (bf16 single; SWAP: blockIdx.x=m, .y=n)
template<int TM, int TN, bool OUTB, int BIAS, bool ACC, bool OUTT, bool SWAP>
__global__ __launch_bounds__(256, 2) void mgemm_k(
    const u16* __restrict__ A, long sA, int lda,
    const u16* __restrict__ B, long sB, int ldb,
    const float* __restrict__ bias,
    float* __restrict__ Cf, u16* __restrict__ Cb,
    int M, int N, int K)
{
  constexpr int WMN = (TM >= 128) ? 2 : 1;
  constexpr int WNN = 4 / WMN;
  constexpr int WTM = TM / WMN, WTN = TN / WNN;
  constexpr int FM = WTM / 16, FN = WTN / 16;
  constexpr int BBASE = TM * 128;
  __shared__ __align__(16) char sm[(TM + TN) * 128];

  const int bz = (int)blockIdx.z;
  const int n0 = (SWAP ? blockIdx.y : blockIdx.x) * TN;
  const int m0 = (SWAP ? blockIdx.x : blockIdx.y) * TM;
  const int tid = threadIdx.x, lane = tid & 63, w = tid >> 6;
  const int wm0 = (w / WNN) * WTM, wn0 = (w % WNN) * WTN;

  bf16x8 rA[TM / 32], rB[TN / 32];
  auto loadA = [&](int k0) {
    const u16* p = A + bz * sA + (long)m0 * lda + k0;
#pragma unroll
    for (int i = 0; i < TM / 32; ++i) {
      const int v = tid + i * 256, row = v >> 3, vc = v & 7;
      rA[i] = *(const bf16x8*)(p + (long)row * lda + vc * 8);
    }
  };
  auto storeA = [&]() {
#pragma unroll
    for (int i = 0; i < TM / 32; ++i) {
      const int v = tid + i * 256, row = v >> 3, vc = v & 7;
      *(bf16x8*)(sm + row * 128 + ((vc * 16) ^ ((row & 7) << 4))) = rA[i];
    }
  };
  auto loadB = [&](int k0) {
    const u16* p = B + bz * sB + (long)n0 * ldb + k0;
#pragma unroll
    for (int i = 0; i < TN / 32; ++i) {
      const int v = tid + i * 256, row = v >> 3, vc = v & 7;
      rB[i] = *(const bf16x8*)(p + (long)row * ldb + vc * 8);
    }
  };
  auto storeB = [&]() {
#pragma unroll
    for (int i = 0; i < TN / 32; ++i) {
      const int v = tid + i * 256, row = v >> 3, vc = v & 7;
      *(bf16x8*)(sm + BBASE + row * 128 + ((vc * 16) ^ ((row & 7) << 4))) = rB[i];
    }
  };

  f32x4 acc[FM][FN];
#pragma unroll
  for (int c = 0; c < FM; ++c)
#pragma unroll
    for (int d = 0; d < FN; ++d) acc[c][d] = (f32x4)(0.0f);

  loadA(0); loadB(0);
  for (int k0 = 0; k0 < K; k0 += 64) {
    storeA(); storeB();
    __syncthreads();
    if (k0 + 64 < K) { loadA(k0 + 64); loadB(k0 + 64); }
#pragma unroll
    for (int s = 0; s < 2; ++s) {
      const int kb = s * 64 + ((lane >> 4) << 4);
      bf16x8 ah[FM], bh[FN];
#pragma unroll
      for (int c = 0; c < FM; ++c) {
        const int ar = wm0 + c * 16 + (lane & 15);
        ah[c] = *(const bf16x8*)(sm + ar * 128 + (kb ^ ((ar & 7) << 4)));
      }
#pragma unroll
      for (int d = 0; d < FN; ++d) {
        const int br = wn0 + d * 16 + (lane & 15);
        bh[d] = *(const bf16x8*)(sm + BBASE + br * 128 + (kb ^ ((br & 7) << 4)));
      }
#pragma unroll
      for (int c = 0; c < FM; ++c)
#pragma unroll
        for (int d = 0; d < FN; ++d)
          acc[c][d] = __builtin_amdgcn_mfma_f32_16x16x32_bf16(ah[c], bh[d], acc[c][d], 0, 0, 0);
    }
    __syncthreads();
  }

  const long cb = (long)bz * M * N;
#pragma unroll
  for (int c = 0; c < FM; ++c)
#pragma unroll
    for (int d = 0; d < FN; ++d) {
      const int row0 = m0 + wm0 + c * 16 + (lane >> 4) * 4;
      const int col = n0 + wn0 + d * 16 + (lane & 15);
      if constexpr (OUTT) {
        u16x4 vv;
#pragma unroll
        for (int r = 0; r < 4; ++r) vv[r] = bf16rn(acc[c][d][r]);
        *(u16x4*)(Cb + cb + (long)col * M + row0) = vv;
      } else {
        float bcol = 0.f;
        if constexpr (BIAS == 1) bcol = bias[col];
#pragma unroll
        for (int r = 0; r < 4; ++r) {
          const int row = row0 + r;
          float v = acc[c][d][r];
          if constexpr (BIAS == 1) v += bcol;
          if constexpr (BIAS == 2) v += bias[row];
          const long idx = cb + (long)row * N + col;
          if constexpr (OUTB) {
            Cb[idx] = bf16rn(v);
          } else {
            if constexpr (ACC) v += Cf[idx];
            Cf[idx] = v;
          }
        }
      }
    }
}

// ------------------------------------------------------------------ shared 64x64 GEMM body (merged QKV)
__device__ __forceinline__ void gemm64_body(char* sm,
    const u16* __restrict__ A, int lda, const u16* __restrict__ B, int ldb,
    const float* __restrict__ bias, u16* __restrict__ Cb,
    int N, int K, int m0, int n0, bool biasRow)
{
  const int tid = threadIdx.x, lane = tid & 63, w = tid >> 6;
  bf16x8 rA[2], rB[2];
  auto loadA = [&](int k0) {
#pragma unroll
    for (int i = 0; i < 2; ++i) {
      const int v = tid + i * 256, row = v >> 3, vc = v & 7;
      rA[i] = *(const bf16x8*)(A + (long)(m0 + row) * lda + k0 + vc * 8);
    }
  };
  auto loadB = [&](int k0) {
#pragma unroll
    for (int i = 0; i < 2; ++i) {
      const int v = tid + i * 256, row = v >> 3, vc = v & 7;
      rB[i] = *(const bf16x8*)(B + (long)(n0 + row) * ldb + k0 + vc * 8);
    }
  };
  auto storeAB = [&]() {
#pragma unroll
    for (int i = 0; i < 2; ++i) {
      const int v = tid + i * 256, row = v >> 3, vc = v & 7;
      const int off = row * 128 + ((vc * 16) ^ ((row & 7) << 4));
      *(bf16x8*)(sm + off) = rA[i];
      *(bf16x8*)(sm + 8192 + off) = rB[i];
    }
  };

  f32x4 acc[4];
#pragma unroll
  for (int c = 0; c < 4; ++c) acc[c] = (f32x4)(0.0f);

  loadA(0); loadB(0);
  for (int k0 = 0; k0 < K; k0 += 64) {
    storeAB();
    __syncthreads();
    if (k0 + 64 < K) { loadA(k0 + 64); loadB(k0 + 64); }
#pragma unroll
    for (int s = 0; s < 2; ++s) {
      const int kb = s * 64 + ((lane >> 4) << 4);
      const int br = w * 16 + (lane & 15);
      const bf16x8 bh = *(const bf16x8*)(sm + 8192 + br * 128 + (kb ^ ((br & 7) << 4)));
#pragma unroll
      for (int c = 0; c < 4; ++c) {
        const int ar = c * 16 + (lane & 15);
        const bf16x8 ah = *(const bf16x8*)(sm + ar * 128 + (kb ^ ((ar & 7) << 4)));
        acc[c] = __builtin_amdgcn_mfma_f32_16x16x32_bf16(ah, bh, acc[c], 0, 0, 0);
      }
    }
    __syncthreads();
  }

  const int col = n0 + w * 16 + (lane & 15);
  const float bcol = biasRow ? 0.f : bias[col];
#pragma unroll
  for (int c = 0; c < 4; ++c) {
    const int row0 = m0 + c * 16 + (lane >> 4) * 4;
#pragma unroll
    for (int r = 0; r < 4; ++r) {
      const int row = row0 + r;
      const float bv = biasRow ? bias[row] : bcol;
      Cb[(long)row * N + col] = bf16rn(acc[c][r] + bv);
    }
  }
}

// 6 merged QKV projections in one dispatch: z = p6*16 + b.
__global__ __launch_bounds__(256, 2) void qkv6_k(
    const u16* __restrict__ CNN, const u16* __restrict__ G3,
    const u16* __restrict__ w0, const u16* __restrict__ w1,
    const u16* __restrict__ w2, const u16* __restrict__ w3,
    const u16* __restrict__ w4, const u16* __restrict__ w5,
    const float* __restrict__ b0, const float* __restrict__ b1,
    const float* __restrict__ b2, const float* __restrict__ b3,
    const float* __restrict__ b4, const float* __restrict__ b5,
    u16* __restrict__ o0, u16* __restrict__ o1,
    u16* __restrict__ o2, u16* __restrict__ o3,
    u16* __restrict__ o4, u16* __restrict__ o5)
{
  __shared__ __align__(16) char sm[16384];
  constexpr long QS = (long)Nn * C3n;
  const int z = blockIdx.z, p6 = z >> 4, b = z & 15;
  const u16* in = (p6 == 0 || p6 == 1 || p6 == 4) ? CNN : G3;
  const u16* W = p6==0?w0:p6==1?w1:p6==2?w2:p6==3?w3:p6==4?w4:w5;
  const float* bias = p6==0?b0:p6==1?b1:p6==2?b2:p6==3?b3:p6==4?b4:b5;
  u16* out = p6==0?o0:p6==1?o1:p6==2?o2:p6==3?o3:p6==4?o4:o5;
  if (p6 < 4) {
    gemm64_body(sm, in + (long)b * QS, C3n, W, C3n, bias, out + (long)b * QS,
                C3n, C3n, blockIdx.y * 64, blockIdx.x * 64, false);
  } else {
    gemm64_body(sm, W, C3n, in + (long)b * QS, C3n, bias, out + (long)b * QS,
                Nn, C3n, blockIdx.x * 64, blockIdx.y * 64, true);
  }
}

// ------------------------------------------------------------------ W-mul + GLU fused GEMM (SWAP: blockIdx.x=m, .y=h)
template<int KC, bool OUTT>
__global__ __launch_bounds__(256, 2) void wglu_k(
    const u16* __restrict__ A, long sA,
    const u16* __restrict__ W,
    const float* __restrict__ bias,
    u16* __restrict__ G, long sG, int H)
{
  __shared__ __align__(16) char sm[3 * 8192];
  const int bz = blockIdx.z;
  const int h0 = blockIdx.y * 64, m0 = blockIdx.x * 64;
  const int tid = threadIdx.x, lane = tid & 63, w = tid >> 6;
  const int wn0 = w * 16;

  f32x4 accO[4], accG[4];
#pragma unroll
  for (int c = 0; c < 4; ++c) { accO[c] = (f32x4)(0.0f); accG[c] = (f32x4)(0.0f); }

  for (int k0 = 0; k0 < KC; k0 += 64) {
#pragma unroll
    for (int i = 0; i < 2; ++i) {
      const int v = tid + i * 256, row = v >> 3, vc = v & 7;
      const int off = row * 128 + ((vc * 16) ^ ((row & 7) << 4));
      *(bf16x8*)(sm + off) = *(const bf16x8*)(A + bz * sA + (long)(m0 + row) * KC + k0 + vc * 8);
      *(bf16x8*)(sm + 8192 + off) = *(const bf16x8*)(W + (long)(h0 + row) * KC + k0 + vc * 8);
      *(bf16x8*)(sm + 16384 + off) = *(const bf16x8*)(W + (long)(H + h0 + row) * KC + k0 + vc * 8);
    }
    __syncthreads();
#pragma unroll
    for (int s = 0; s < 2; ++s) {
      const int kb = s * 64 + ((lane >> 4) << 4);
      const int br = wn0 + (lane & 15);
      const bf16x8 bo = *(const bf16x8*)(sm + 8192 + br * 128 + (kb ^ ((br & 7) << 4)));
      const bf16x8 bg = *(const bf16x8*)(sm + 16384 + br * 128 + (kb ^ ((br & 7) << 4)));
#pragma unroll
      for (int c = 0; c < 4; ++c) {
        const int ar = c * 16 + (lane & 15);
        const bf16x8 a = *(const bf16x8*)(sm + ar * 128 + (kb ^ ((ar & 7) << 4)));
        accO[c] = __builtin_amdgcn_mfma_f32_16x16x32_bf16(a, bo, accO[c], 0, 0, 0);
        accG[c] = __builtin_amdgcn_mfma_f32_16x16x32_bf16(a, bg, accG[c], 0, 0, 0);
      }
    }
    __syncthreads();
  }

  const int col = h0 + wn0 + (lane & 15);
  const float bo = bias[col], bg = bias[H + col];
#pragma unroll
  for (int c = 0; c < 4; ++c) {
    const int row0 = m0 + c * 16 + (lane >> 4) * 4;
    if constexpr (OUTT) {
      u16x4 vv;
#pragma unroll
      for (int r = 0; r < 4; ++r) {
        const float o = accO[c][r] + bo, g = accG[c][r] + bg;
        vv[r] = bf16rn(o / (1.f + expf(-g)));
      }
      *(u16x4*)(G + bz * sG + (long)col * Nn + row0) = vv;
    } else {
#pragma unroll
      for (int r = 0; r < 4; ++r) {
        const float o = accO[c][r] + bo, g = accG[c][r] + bg;
        G[bz * sG + (long)(row0 + r) * H + col] = bf16rn(o / (1.f + expf(-g)));
      }
    }
  }
}

// ------------------------------------------------------------------ conv1d k=7 + fused GLU epilogue (R23-proven)
__global__ __launch_bounds__(256, 2) void conv_mfma_k(
    const u16* __restrict__ Wp, const u16* __restrict__ in_nm, int ldin, long sIn,
    const float* __restrict__ bias,
    u16* __restrict__ G, int Ci, int M)
{
  __shared__ __align__(16) char sm[9216 + 7 * 8192];
  const int bz = blockIdx.z;
  const int n0 = blockIdx.x * 64, m0 = blockIdx.y * 64;
  const int tid = threadIdx.x, lane = tid & 63, w = tid >> 6;
  const int wm = (w >> 1) * 32, wn = (w & 1) * 32;
  const u16* inb = in_nm + bz * sIn;

  f32x4 acc[2][2];
#pragma unroll
  for (int c = 0; c < 2; ++c)
#pragma unroll
    for (int d = 0; d < 2; ++d) acc[c][d] = (f32x4)(0.0f);

  for (int k0 = 0; k0 < Ci; k0 += 64) {
#pragma unroll
    for (int r = 0; r < 3; ++r) {
      const int idx = r * 256 + tid;
      if (idx < 576) {
        const int row = idx >> 3, ch = idx & 7;
        const int g = n0 + row - 3;
        bf16x8 v;
#pragma unroll
        for (int j = 0; j < 8; ++j) v[j] = 0;
        if ((unsigned)g < (unsigned)Nn)
          v = *(const bf16x8*)(inb + (long)g * ldin + k0 + ch * 8);
        *(bf16x8*)(sm + row * 128 + ((ch * 16) ^ ((row & 7) << 4))) = v;
      }
    }
#pragma unroll
    for (int i = 0; i < 14; ++i) {
      const int v = tid + i * 256;
      const int ft = v >> 9, rr = (v >> 3) & 63, vc = v & 7;
      const bf16x8 t = *(const bf16x8*)(Wp + ((long)ft * M + m0 + rr) * Ci + k0 + vc * 8);
      *(bf16x8*)(sm + 9216 + ft * 8192 + rr * 128 + ((vc * 16) ^ ((rr & 7) << 4))) = t;
    }
    __syncthreads();
#pragma unroll
    for (int ft = 0; ft < 7; ++ft) {
#pragma unroll
      for (int s = 0; s < 2; ++s) {
        const int kb = s * 64 + ((lane >> 4) << 4);
        bf16x8 ah[2], bh[2];
#pragma unroll
        for (int c = 0; c < 2; ++c) {
          const int ar = wm + c * 16 + (lane & 15);
          ah[c] = *(const bf16x8*)(sm + 9216 + ft * 8192 + ar * 128 + (kb ^ ((ar & 7) << 4)));
          const int hr = wn + c * 16 + (lane & 15) + ft;
          bh[c] = *(const bf16x8*)(sm + hr * 128 + (kb ^ ((hr & 7) << 4)));
        }
#pragma unroll
        for (int c = 0; c < 2; ++c)
#pragma unroll
          for (int d = 0; d < 2; ++d)
            acc[c][d] = __builtin_amdgcn_mfma_f32_16x16x32_bf16(ah[c], bh[d], acc[c][d], 0, 0, 0);
      }
    }
    __syncthreads();
  }

  const int Hh = M >> 1;
  u16* Gb = G + (long)bz * Nn * Hh;
#pragma unroll
  for (int c = 0; c < 2; ++c)
#pragma unroll
    for (int d = 0; d < 2; ++d) {
      const int row0 = m0 + wm + c * 16 + (lane >> 4) * 4;
      const int col = n0 + wn + d * 16 + (lane & 15);
      const int h0 = row0 >> 1;
#pragma unroll
      for (int i = 0; i < 2; ++i) {
        const int h = h0 + i;
        const float o = acc[c][d][2 * i]     + bias[h];
        const float g = acc[c][d][2 * i + 1] + bias[Hh + h];
        Gb[(long)col * Hh + h] = bf16rn(o / (1.f + expf(-g)));
      }
    }
}

// ------------------------------------------------------------------ fused flash attention, 8-wave blocks (128 q-rows)
// LDS: K@0 24KB | V@24576 24KB | P@49152 16KB = 64KB -> 2 blocks/CU (16 waves).
// launch_bounds(512,2): VGPR cap 256 -> natural ~110-130 alloc, no spills.
// Body correctness verified in R21. XCD-local grid (combo, qb in 0..8).
__global__ __launch_bounds__(512, 2) void attn_k(
    const u16* __restrict__ Q0, const u16* __restrict__ K0,
    const u16* __restrict__ V0,
    const u16* __restrict__ Q1, const u16* __restrict__ K1,
    const u16* __restrict__ V1,
    float* __restrict__ PSUM)
{
  constexpr long QS = (long)Nn * C3n;
  constexpr int SMV = 24576, SMP = 49152;
  __shared__ __align__(16) char sm[65536];
  const int combo = blockIdx.x, qb = blockIdx.y;
  const int b = combo & 15, at = combo >> 4;
  const u16* Q = (at ? Q1 : Q0) + (long)b * QS + (long)qb * 128 * C3n;
  const u16* K = (at ? K1 : K0) + (long)b * QS;
  const u16* V = (at ? V1 : V0) + (long)b * QS;
  const int tid = threadIdx.x, lane = tid & 63, w = tid >> 6; // w in 0..7

  bf16x8 vone;
#pragma unroll
  for (int j = 0; j < 8; ++j) vone[j] = (short)0x3F80;

  // Q A-fragments in registers (wave w owns q-rows [16w,16w+16))
  bf16x8 rQ[6];
  {
    const int qrow = w * 16 + (lane & 15);
#pragma unroll
    for (int s = 0; s < 6; ++s)
      rQ[s] = *(const bf16x8*)(Q + (long)qrow * C3n + s * 32 + ((lane >> 4) << 3));
  }

  bf16x8 rK[3], rV[3];
  auto loadK = [&](int kb) {
    const int row = tid >> 3;              // 0..63
#pragma unroll
    for (int j = 0; j < 3; ++j) {
      const int ch = (tid & 7) + j * 8;    // 0..23
      rK[j] = *(const bf16x8*)(K + ((long)kb * 64 + row) * C3n + ch * 8);
    }
  };
  auto storeK = [&]() {
    const int row = tid >> 3;
#pragma unroll
    for (int j = 0; j < 3; ++j) {
      const int ch = (tid & 7) + j * 8;
      *(bf16x8*)(sm + row * 384 + ((ch * 16) ^ ((row & 7) << 4))) = rK[j];
    }
  };
  auto loadV = [&](int kb) {
#pragma unroll
    for (int j = 0; j < 3; ++j) {
      const int row = (tid >> 3) + j * 64; // channel 0..191
      const int ch = tid & 7;
      rV[j] = *(const bf16x8*)(V + (long)row * Nn + kb * 64 + ch * 8);
    }
  };
  auto storeV = [&]() {
#pragma unroll
    for (int j = 0; j < 3; ++j) {
      const int row = (tid >> 3) + j * 64;
      const int ch = tid & 7;
      *(bf16x8*)(sm + SMV + row * 128 + ((ch * 16) ^ ((row & 7) << 4))) = rV[j];
    }
  };

  f32x4 accO[12], accL;
#pragma unroll
  for (int f = 0; f < 12; ++f) accO[f] = (f32x4)(0.0f);
  accL = (f32x4)(0.0f);
  float m[4];
#pragma unroll
  for (int r = 0; r < 4; ++r) m[r] = -3.0e38f;

  loadK(0);
  for (int kb = 0; kb < 16; ++kb) {
    storeK();
    __syncthreads();                 // B1: K visible
    loadV(kb);

    f32x4 accS[4];
#pragma unroll
    for (int d = 0; d < 4; ++d) accS[d] = (f32x4)(0.0f);
    __builtin_amdgcn_s_setprio(1);
#pragma unroll
    for (int s = 0; s < 6; ++s) {
      const int kpos = s * 64 + ((lane >> 4) << 4);
#pragma unroll
      for (int d = 0; d < 4; ++d) {
        const int br = d * 16 + (lane & 15);
        const bf16x8 bb = *(const bf16x8*)(sm + br * 384 + (kpos ^ ((br & 7) << 4)));
        accS[d] = __builtin_amdgcn_mfma_f32_16x16x32_bf16(rQ[s], bb, accS[d], 0, 0, 0);
      }
    }
    __builtin_amdgcn_s_setprio(0);

    // online softmax, defer-max THR=8 (T13); row-sum l via ones-MFMA
    float fac[4];
    bool need = false;
#pragma unroll
    for (int r = 0; r < 4; ++r) {
      float mx = fmaxf(fmaxf(accS[0][r], accS[1][r]), fmaxf(accS[2][r], accS[3][r]));
#pragma unroll
      for (int off = 8; off; off >>= 1) mx = fmaxf(mx, __shfl_xor(mx, off));
      float mn;
      if (mx > m[r] + 8.f) {
        mn = mx;
        fac[r] = __expf(m[r] - mn);
        m[r] = mn;
        need = true;
      } else {
        mn = m[r];
        fac[r] = 1.f;
      }
#pragma unroll
      for (int d = 0; d < 4; ++d) {
        float e = __expf(accS[d][r] - mn);
        if (e != e) e = (accS[d][r] == mn) ? 1.f : 0.f;
        accS[d][r] = e;
      }
    }
    if (__any(need)) {
#pragma unroll
      for (int f = 0; f < 12; ++f)
#pragma unroll
        for (int r = 0; r < 4; ++r) accO[f][r] *= fac[r];
#pragma unroll
      for (int r = 0; r < 4; ++r) accL[r] *= fac[r];
    }

    {
      const int qbase = w * 16 + (lane >> 4) * 4;
#pragma unroll
      for (int r = 0; r < 4; ++r) {
        const int qr = qbase + r;              // 0..127
#pragma unroll
        for (int d = 0; d < 4; ++d) {
          const int colb = (d * 16 + (lane & 15)) * 2;
          *(u16*)(sm + SMP + qr * 128 + (colb ^ ((qr & 7) << 4))) = bf16rn(accS[d][r]);
        }
      }
    }
    storeV();
    __syncthreads();                 // B2: P and V visible
    if (kb < 15) loadK(kb + 1);

    __builtin_amdgcn_s_setprio(1);
#pragma unroll
    for (int s = 0; s < 2; ++s) {
      const int kpos = s * 64 + ((lane >> 4) << 4);
      const int ar = w * 16 + (lane & 15);     // 0..127
      const bf16x8 a = *(const bf16x8*)(sm + SMP + ar * 128 + (kpos ^ ((ar & 7) << 4)));
#pragma unroll
      for (int f = 0; f < 12; ++f) {
        const int br = f * 16 + (lane & 15);
        const bf16x8 bb = *(const bf16x8*)(sm + SMV + br * 128 + (kpos ^ ((br & 7) << 4)));
        accO[f] = __builtin_amdgcn_mfma_f32_16x16x32_bf16(a, bb, accO[f], 0, 0, 0);
      }
      accL = __builtin_amdgcn_mfma_f32_16x16x32_bf16(a, vone, accL, 0, 0, 0);
    }
    __builtin_amdgcn_s_setprio(0);
  }

  // epilogue: reduce 128 q-rows to 192-channel partial sums -> PSUM
  float inv[4];
#pragma unroll
  for (int r = 0; r < 4; ++r) inv[r] = NORM_C / accL[r];
  float s[12];
#pragma unroll
  for (int f = 0; f < 12; ++f) {
    s[f] = accO[f][0] * inv[0] + accO[f][1] * inv[1]
         + accO[f][2] * inv[2] + accO[f][3] * inv[3];
    s[f] += __shfl_xor(s[f], 16);
    s[f] += __shfl_xor(s[f], 32);
  }
  __syncthreads();                  // all PV reads done; K region dead
  float* red = (float*)sm;          // [8][192] = 6KB in dead K region
  if ((lane >> 4) == 0) {
#pragma unroll
    for (int f = 0; f < 12; ++f) red[w * 192 + f * 16 + (lane & 15)] = s[f];
  }
  __syncthreads();
  if (tid < 192) {
    float t = 0.f;
#pragma unroll
    for (int ww = 0; ww < 8; ++ww) t += red[ww * 192 + tid];
    PSUM[(((long)at * 16 + b) * 8 + qb) * 192 + tid] = t;
  }
}

// ------------------------------------------------------------------ merged converters
__global__ void cvt2_k(const float* __restrict__ a, const float* __restrict__ b,
                       u16* __restrict__ da, u16* __restrict__ db, long half4)
{
  const long i = (long)blockIdx.x * 256 + threadIdx.x;
  if (i >= 2 * half4) return;
  const bool second = (i >= half4);
  const long j = second ? i - half4 : i;
  float4 v = ((const float4*)(second ? b : a))[j];
  u16x4 o = {bf16rn(v.x), bf16rn(v.y), bf16rn(v.z), bf16rn(v.w)};
  ((u16x4*)(second ? db : da))[j] = o;
}

__global__ void xcvt2_k(const float* __restrict__ x, u16* __restrict__ xh,
                        u16* __restrict__ xc)
{
  __shared__ float t[32][33];
  const int b = blockIdx.z;
  const int n0 = blockIdx.x * 32, c0 = blockIdx.y * 32;
  const int tx = threadIdx.x, ty = threadIdx.y;
#pragma unroll
  for (int i = 0; i < 32; i += 8) {
    const float v = x[((long)b * Nn + n0 + ty + i) * 128 + c0 + tx];
    t[ty + i][tx] = v;
    xh[((long)b * Nn + n0 + ty + i) * 128 + c0 + tx] = bf16rn(v);
  }
  __syncthreads();
#pragma unroll
  for (int i = 0; i < 32; i += 8)
    xc[((long)b * 128 + c0 + ty + i) * Nn + n0 + tx] = bf16rn(t[tx][ty + i]);
}

// 12 merged weight-prep jobs; conv Wp rows interleaved (2h / 2h+1)
__global__ void prep12_k(
    const float* c1w, const float* c2w, const float* c3w,
    u16* wp1, u16* wp2, u16* wp3,
    const float* q0, const float* q1, const float* q2,
    const float* q3, const float* q4, const float* q5,
    u16* d0, u16* d1, u16* d2, u16* d3, u16* d4, u16* d5,
    const float* g1w, const float* g2w, const float* g3w,
    u16* w1t, u16* w2t, u16* w3t)
{
  const int job = blockIdx.y;
  const int idx = blockIdx.x * 256 + threadIdx.x;
  if (job < 3) {
    const float* w = job == 0 ? c1w : job == 1 ? c2w : c3w;
    u16* Wp = job == 0 ? wp1 : job == 1 ? wp2 : wp3;
    const int Co = job == 0 ? 128 : job == 1 ? 256 : 384;
    const int Ci = job == 1 ? 64 : 128;
    if (idx >= Co * Ci * 7) return;
    const int ft = idx / (Co * Ci);
    const int rem = idx - ft * Co * Ci;
    const int co = rem / Ci, ci = rem - co * Ci;
    const int Hh = Co >> 1;
    const int rnew = (co < Hh) ? (2 * co) : (2 * (co - Hh) + 1);
    Wp[((long)ft * Co + rnew) * Ci + ci] = bf16rn(w[((long)co * Ci + ci) * 7 + ft]);
  } else if (job < 9) {
    const int q = job - 3;
    const float* s = q==0?q0:q==1?q1:q==2?q2:q==3?q3:q==4?q4:q5;
    u16* d = q==0?d0:q==1?d1:q==2?d2:q==3?d3:q==4?d4:d5;
    if (idx >= 192 * 192) return;
    d[idx] = bf16rn(s[idx]);
  } else {
    const int t = job - 9;
    const float* W = t == 0 ? g1w : t == 1 ? g2w : g3w;
    u16* Wt = t == 0 ? w1t : t == 1 ? w2t : w3t;
    const int R = t == 0 ? 128 : t == 1 ? 64 : 128;
    const int C = t == 0 ? 128 : t == 1 ? 256 : 384;
    if (idx >= R * C) return;
    const int c = idx / R, r = idx - c * R;
    Wt[idx] = bf16rn(W[(long)r * C + c]);
  }
}

// ------------------------------------------------------------------ head (sums PSUM partials, 8 qb)
__device__ __forceinline__ float sanitize(float v)
{
  if (v != v) return 0.f;
  return fminf(fmaxf(v, -3.0e38f), 3.0e38f);
}

__global__ void head_k(const float* __restrict__ psum,
                       const float* __restrict__ l1w, const float* __restrict__ l1b,
                       const float* __restrict__ l2w, const float* __restrict__ l2b,
                       const float* __restrict__ eps, float* __restrict__ out)
{
  const int b = blockIdx.x, o = threadIdx.x;
  __shared__ float sp[C3n];
  float sacc = 0.f;
#pragma unroll
  for (int at = 0; at < 2; ++at)
    for (int q = 0; q < 8; ++q)
      sacc += psum[(((long)at * 16 + b) * 8 + q) * 192 + o];
  sp[o] = sacc * (1.f / Nn);
  __syncthreads();
  float d1 = l1b[o], d2 = l2b[o];
  for (int c = 0; c < C3n; ++c) {
    d1 = fmaf(sp[c], l1w[o * C3n + c], d1);
    d2 = fmaf(sp[c], l2w[o * C3n + c], d2);
  }
  const float o1 = fmaxf(d1, 0.f);
  const float o2 = fmaxf(d2, 0.f);
  const float sd = fminf(expf(0.5f * o2), 3.0e38f);
  const double v0 = (double)eps[b * C3n + o] * (double)sd + (double)o1;
  out[b * C3n + o] = sanitize((float)fmin(fmax(v0, -3.0e38), 3.0e38));
  out[Bn * C3n + b * C3n + o] = sanitize(o1);
  out[2 * Bn * C3n + b * C3n + o] = sanitize(o2);
}

// ------------------------------------------------------------------ launch
extern "C" void kernel_launch(void* const* d_in, const int* in_sizes, int n_in,
                              void* d_out, int out_size, void* d_ws, size_t ws_size,
                              hipStream_t stream)
{
  const float* x    = (const float*)d_in[0];
  const float* adjm = (const float*)d_in[1];
  const float* deg  = (const float*)d_in[2];
  const float* eps  = (const float*)d_in[3];
  const float* g1w  = (const float*)d_in[4];
  const float* g1b  = (const float*)d_in[5];
  const float* g2w  = (const float*)d_in[6];
  const float* g2b  = (const float*)d_in[7];
  const float* g3w  = (const float*)d_in[8];
  const float* g3b  = (const float*)d_in[9];
  const float* c1w  = (const float*)d_in[10];
  const float* c1b  = (const float*)d_in[11];
  const float* c2w  = (const float*)d_in[12];
  const float* c2b  = (const float*)d_in[13];
  const float* c3w  = (const float*)d_in[14];
  const float* c3b  = (const float*)d_in[15];
  const float* srqw = (const float*)d_in[16];
  const float* srqb = (const float*)d_in[17];
  const float* srkw = (const float*)d_in[18];
  const float* srkb = (const float*)d_in[19];
  const float* srvw = (const float*)d_in[20];
  const float* srvb = (const float*)d_in[21];
  const float* drqw = (const float*)d_in[22];
  const float* drqb = (const float*)d_in[23];
  const float* drkw = (const float*)d_in[24];
  const float* drkb = (const float*)d_in[25];
  const float* drvw = (const float*)d_in[26];
  const float* drvb = (const float*)d_in[27];
  const float* l1w  = (const float*)d_in[28];
  const float* l1b  = (const float*)d_in[29];
  const float* l2w  = (const float*)d_in[30];
  const float* l2b  = (const float*)d_in[31];
  float* out = (float*)d_out;
  char* ws = (char*)d_ws;

  constexpr long MBc = 1L << 20;
  u16*  DEGB = (u16*)(ws + 0*MBc);
  u16*  ADJB = (u16*)(ws + 34*MBc);
  u16*  c1b16= (u16*)(ws + 94*MBc);
  u16*  c2b16= (u16*)(ws + 97*MBc);
  u16*  T1   = (u16*)(ws + 94*MBc);
  u16*  T2   = (u16*)(ws + 99*MBc);
  u16*  Pb   = (u16*)(ws + 104*MBc);
  u16*  CNN  = (u16*)(ws + 109*MBc);
  u16*  G3   = (u16*)(ws + 116*MBc);
  u16*  xh   = (u16*)(ws + 123*MBc);
  u16*  xch  = (u16*)(ws + 128*MBc);
  u16*  G1   = (u16*)(ws + 133*MBc);
  u16*  G2   = (u16*)(ws + 136*MBc);
  u16*  SRQ = (u16*)(ws + 0*MBc);
  u16*  SRK = (u16*)(ws + 7*MBc);
  u16*  DRQ = (u16*)(ws + 14*MBc);
  u16*  DRK = (u16*)(ws + 21*MBc);
  u16*  SRV = (u16*)(ws + 28*MBc);
  u16*  DRV = (u16*)(ws + 35*MBc);
  float* PSUM = (float*)(ws + 43*MBc); // [2][16][8][192] = 196KB

  long wb = 141 * MBc;
  auto aU = [&](long elems) { u16* p = (u16*)(ws + wb); wb += elems * 2; wb = (wb + 255) & ~255L; return p; };
  u16* W1t = aU(128*128);
  u16* W2t = aU(256*64);
  u16* W3t = aU(384*128);
  u16* WP1 = aU(7*128*128);
  u16* WP2 = aU(7*256*64);
  u16* WP3 = aU(7*384*128);
  u16* QW[6];
  for (int i = 0; i < 6; ++i) QW[i] = aU(192*192);

  const long sNN = (long)Nn * Nn;
  const long QS = (long)Nn * C3n;
  const long sCM128 = (long)128 * Nn;

  // ---------------- P0: conversions + weight prep + CNN branch ----------------
  cvt2_k<<<32768, 256, 0, stream>>>(deg, adjm, DEGB, ADJB, sNN * Bn / 4);
  xcvt2_k<<<dim3(32,4,Bn), dim3(32,8), 0, stream>>>(x, xh, xch);
  prep12_k<<<dim3(1344, 12), 256, 0, stream>>>(
      c1w, c2w, c3w, WP1, WP2, WP3,
      srqw, srkw, srvw, drqw, drkw, drvw,
      QW[0], QW[1], QW[2], QW[3], QW[4], QW[5],
      g1w, g2w, g3w, W1t, W2t, W3t);

  // conv chain with fused GLU epilogue (direct [n][H] bf16 outputs)
  conv_mfma_k<<<dim3(16,2,Bn), 256, 0, stream>>>(WP1, xh, 128, (long)Nn*128, c1b, c1b16, 128, 128);
  conv_mfma_k<<<dim3(16,4,Bn), 256, 0, stream>>>(WP2, c1b16, 64, (long)Nn*64, c2b, c2b16, 64, 256);
  conv_mfma_k<<<dim3(16,6,Bn), 256, 0, stream>>>(WP3, c2b16, 128, (long)Nn*128, c3b, CNN, 128, 384);

  // ---------------- P1: GCN chain (XCD-local m-major grids) ----------------
  mgemm_k<64,64,false,0,false,true,true><<<dim3(16,2,Bn), 256, 0, stream>>>(
      DEGB, sNN, Nn, xch, sCM128, Nn, nullptr, nullptr, T1, Nn, 128, Nn);
  mgemm_k<64,64,false,0,false,true,true><<<dim3(16,2,Bn), 256, 0, stream>>>(
      ADJB, sNN, Nn, T1, sCM128, Nn, nullptr, nullptr, T2, Nn, 128, Nn);
  mgemm_k<64,64,true,0,false,false,true><<<dim3(16,2,Bn), 256, 0, stream>>>(
      DEGB, sNN, Nn, T2, sCM128, Nn, nullptr, nullptr, Pb, Nn, 128, Nn);
  wglu_k<128,true><<<dim3(16,1,Bn), 256, 0, stream>>>(
      Pb, (long)Nn*128, W1t, g1b, G1, (long)64*Nn, 64);
  mgemm_k<64,64,false,0,false,true,true><<<dim3(16,1,Bn), 256, 0, stream>>>(
      DEGB, sNN, Nn, G1, (long)64*Nn, Nn, nullptr, nullptr, T1, Nn, 64, Nn);
  mgemm_k<64,64,false,0,false,true,true><<<dim3(16,1,Bn), 256, 0, stream>>>(
      ADJB, sNN, Nn, T1, (long)64*Nn, Nn, nullptr, nullptr, T2, Nn, 64, Nn);
  mgemm_k<64,64,true,0,false,false,true><<<dim3(16,1,Bn), 256, 0, stream>>>(
      DEGB, sNN, Nn, T2, (long)64*Nn, Nn, nullptr, nullptr, Pb, Nn, 64, Nn);
  wglu_k<64,true><<<dim3(16,2,Bn), 256, 0, stream>>>(
      Pb, (long)Nn*64, W2t, g2b, G2, sCM128, 128);
  mgemm_k<64,64,false,0,false,true,true><<<dim3(16,2,Bn), 256, 0, stream>>>(
      DEGB, sNN, Nn, G2, sCM128, Nn, nullptr, nullptr, T1, Nn, 128, Nn);
  mgemm_k<64,64,false,0,false,true,true><<<dim3(16,2,Bn), 256, 0, stream>>>(
      ADJB, sNN, Nn, T1, sCM128, Nn, nullptr, nullptr, T2, Nn, 128, Nn);
  mgemm_k<64,64,true,0,false,false,true><<<dim3(16,2,Bn), 256, 0, stream>>>(
      DEGB, sNN, Nn, T2, sCM128, Nn, nullptr, nullptr, Pb, Nn, 128, Nn);
  wglu_k<128,false><<<dim3(16,3,Bn), 256, 0, stream>>>(
      Pb, (long)Nn*128, W3t, g3b, G3, QS, 192);

  // ---------------- P2: merged QKV (one dispatch, 6 projections) ----------------
  qkv6_k<<<dim3(3,16,96), 256, 0, stream>>>(
      CNN, G3, QW[0], QW[1], QW[3], QW[4], QW[2], QW[5],
      srqb, srkb, drqb, drkb, srvb, drvb,
      SRQ, SRK, DRQ, DRK, SRV, DRV);

  // ---------------- P3: fused dual attention (8-wave, XCD-local) ----------------
  attn_k<<<dim3(32, 8, 1), 512, 0, stream>>>(
      SRQ, DRK, SRV, DRQ, SRK, DRV, PSUM);

  // ---------------- head ----------------
  head_k<<<Bn, C3n, 0, stream>>>(PSUM, l1w, l1b, l2w, l2b, eps, out);
}